// Round 6
// baseline (264.702 us; speedup 1.0000x reference)
//
#include <hip/hip_runtime.h>
#include <hip/hip_bf16.h>

#define EMBED 768
#define HEADS 12
#define WIN 64
#define DH 64
#define KDIM 768
#define NTILE 12      // KDIM / 64

typedef unsigned short u16;
typedef unsigned int u32;
typedef __attribute__((ext_vector_type(8))) short bf16x8;
typedef __attribute__((ext_vector_type(4))) float f32x4;
typedef __attribute__((ext_vector_type(16))) float f32x16;

__device__ __forceinline__ u16 f2bf(float f) {
  union { float f; u32 u; } x; x.f = f;
  return (u16)((x.u + 0x7fffu + ((x.u >> 16) & 1u)) >> 16);
}

// ---------------- fp32 -> bf16 convert ----------------
__global__ void cvt_f32_bf16(const float* __restrict__ in, u16* __restrict__ out, int n4) {
  int i = blockIdx.x * blockDim.x + threadIdx.x;
  if (i >= n4) return;
  float4 v = ((const float4*)in)[i];
  ushort4 o;
  o.x = f2bf(v.x); o.y = f2bf(v.y); o.z = f2bf(v.z); o.w = f2bf(v.w);
  ((ushort4*)out)[i] = o;
}

__global__ void concat_bias(const float* __restrict__ bq, const float* __restrict__ bk,
                            const float* __restrict__ bv, float* __restrict__ out) {
  int i = blockIdx.x * 256 + threadIdx.x;
  if (i < 768) out[i] = bq[i];
  else if (i < 1536) out[i] = bk[i - 768];
  else if (i < 2304) out[i] = bv[i - 1536];
}

// ---------------- 256xBN pipelined NT GEMM (K=768), 32x32x16 MFMA ----------------
// BM=256, BN=BNW*64, BK=64, 512 thr = 8 waves (2M x 4N); per-wave 128 x BNW*16*... 
// per-wave out = 128 x (BNW/2)*32 cols... (BNW=4 -> 128x64, NF=2; BNW=2 -> 128x32, NF=1).
// 32x32x16 frags: A/B lane row=lane&31, k=(lane>>5)*8+j; C/D col=lane&31,
// row=(reg&3)+8*(reg>>2)+4*(lane>>5). Reg read-ahead (A one k-step ahead, B
// once/tile). STAGE(t+2) at phase 2 behind buffer-release barrier; counted
// vmcnt at boundary (T4). T1 XCD swizzle, T2 XOR-LDS, T5 setprio.
template<int BNW, bool OUT_F32>
__global__ __launch_bounds__(512, 1)
void gemm256(const u16* __restrict__ A, const u16* __restrict__ Bw,
             const float* __restrict__ bias,
             u16* __restrict__ dQ, u16* __restrict__ dK, u16* __restrict__ dV,
             float* __restrict__ dF, int N) {
  constexpr int BN = BNW * 64;
  constexpr int NF = BNW / 2;                    // 32-col frags per wave
  constexpr int BBUF = BN * 128;                 // bytes per B K-tile
  __shared__ char sc_[65536 + 2 * BBUF];
  const int tid = threadIdx.x;
  const int lane = tid & 63;
  const int wid = tid >> 6;
  const int wr = wid >> 2, wc = wid & 3;
  const int l31 = lane & 31;
  const int g = lane >> 5;

  const int nbx = N / BN;
  const int cpx = gridDim.x >> 3;
  int bid = blockIdx.x;
  bid = (bid & 7) * cpx + (bid >> 3);            // bijective: grid % 8 == 0
  const int brow = (bid / nbx) << 8;
  const int bcol = (bid % nbx) * BN;

  // staging source (per-thread), pre-swizzled global col (T2, rule 21)
  const int srow = tid >> 3;
  const int scol = ((tid & 7) ^ (srow & 7)) << 3;
  const u16* Asrc = A + (size_t)(brow + srow) * KDIM + scol;
  const u16* Bsrc = Bw + (size_t)(bcol + srow) * KDIM + scol;
  const int lds_woff = wid << 10;

  auto STAGE = [&](int b, int kt) {
    char* ab = sc_ + b * 32768;
    char* bb = sc_ + 65536 + b * BBUF;
#pragma unroll
    for (int i = 0; i < 4; ++i)
      __builtin_amdgcn_global_load_lds(
          (const __attribute__((address_space(1))) void*)(Asrc + (size_t)(i << 6) * KDIM + kt),
          (__attribute__((address_space(3))) void*)(ab + (i << 13) + lds_woff), 16, 0, 0);
#pragma unroll
    for (int i = 0; i < BNW; ++i)
      __builtin_amdgcn_global_load_lds(
          (const __attribute__((address_space(1))) void*)(Bsrc + (size_t)(i << 6) * KDIM + kt),
          (__attribute__((address_space(3))) void*)(bb + (i << 13) + lds_woff), 16, 0, 0);
  };

  // k-chunk byte offset (XOR-swizzled) for k-step s: chunk = 2s+g, swz = lane&7
  int kc[4];
#pragma unroll
  for (int s = 0; s < 4; ++s) kc[s] = (((s << 1) + g) << 4) ^ ((lane & 7) << 4);

  f32x16 acc[4][NF];
#pragma unroll
  for (int m = 0; m < 4; ++m)
#pragma unroll
    for (int n = 0; n < NF; ++n)
#pragma unroll
      for (int r = 0; r < 16; ++r) acc[m][n][r] = 0.f;

  bf16x8 RA[2][4];                               // [set][m-frag]
  bf16x8 RB[NF][4];                              // [n-frag][k-step]

  const int wcb = wc * (NF << 5);                // wave's B-row / out-col base
  auto pA = [&](int b, int mi, int s) -> const char* {
    return sc_ + b * 32768 + (wr << 14) + ((mi << 5) + l31) * 128 + kc[s];
  };
  auto pB = [&](int b, int nj, int s) -> const char* {
    return sc_ + 65536 + b * BBUF + (wcb + (nj << 5) + l31) * 128 + kc[s];
  };

  // ---- prologue: stage tiles 0,1; wait tile 0 only ----
  STAGE(0, 0);
  STAGE(1, 64);
  if constexpr (BNW == 4) asm volatile("s_waitcnt vmcnt(8)" ::: "memory");
  else                    asm volatile("s_waitcnt vmcnt(6)" ::: "memory");
  __builtin_amdgcn_sched_barrier(0);
  __builtin_amdgcn_s_barrier();
#pragma unroll
  for (int mi = 0; mi < 4; ++mi) RA[0][mi] = *(const bf16x8*)pA(0, mi, 0);
#pragma unroll
  for (int nj = 0; nj < NF; ++nj)
#pragma unroll
    for (int s = 0; s < 4; ++s) RB[nj][s] = *(const bf16x8*)pB(0, nj, s);

#pragma unroll 2
  for (int t = 0; t < NTILE; ++t) {
    const int b = t & 1;
    // ---- phases s=0,1,2: read k-step s+1, MFMA k-step s ----
#pragma unroll
    for (int s = 0; s < 3; ++s) {
      const int cur = s & 1, nxt = cur ^ 1;
#pragma unroll
      for (int mi = 0; mi < 4; ++mi) RA[nxt][mi] = *(const bf16x8*)pA(b, mi, s + 1);
      if (s == 2 && t + 2 < NTILE) {
        __builtin_amdgcn_s_barrier();            // all waves done reading buf b
        STAGE(b, (t + 2) << 6);                  // t+2 lands under t+1 compute
      }
      __builtin_amdgcn_s_setprio(1);
#pragma unroll
      for (int nj = 0; nj < NF; ++nj)
#pragma unroll
        for (int mi = 0; mi < 4; ++mi)
          acc[mi][nj] = __builtin_amdgcn_mfma_f32_32x32x16_bf16(RA[cur][mi], RB[nj][s], acc[mi][nj], 0, 0, 0);
      __builtin_amdgcn_s_setprio(0);
    }
    // ---- tile boundary (phase s=3) ----
    if (t + 1 < NTILE) {
      if (t + 2 < NTILE) {                       // counted: t+2's loads stay in flight
        if constexpr (BNW == 4) asm volatile("s_waitcnt vmcnt(8)" ::: "memory");
        else                    asm volatile("s_waitcnt vmcnt(6)" ::: "memory");
      } else {
        asm volatile("s_waitcnt vmcnt(0)" ::: "memory");
      }
      __builtin_amdgcn_sched_barrier(0);
      __builtin_amdgcn_s_barrier();              // t+1 landed for all waves
#pragma unroll
      for (int mi = 0; mi < 4; ++mi) RA[0][mi] = *(const bf16x8*)pA(b ^ 1, mi, 0);
      asm volatile("s_waitcnt lgkmcnt(4)" ::: "memory");   // phase-2 RA done
      __builtin_amdgcn_sched_barrier(0);
    } else {
      asm volatile("s_waitcnt lgkmcnt(0)" ::: "memory");
      __builtin_amdgcn_sched_barrier(0);
    }
    __builtin_amdgcn_s_setprio(1);
#pragma unroll
    for (int nj = 0; nj < NF; ++nj)
#pragma unroll
      for (int mi = 0; mi < 4; ++mi)
        acc[mi][nj] = __builtin_amdgcn_mfma_f32_32x32x16_bf16(RA[1][mi], RB[nj][3], acc[mi][nj], 0, 0, 0);
    __builtin_amdgcn_s_setprio(0);
    if (t + 1 < NTILE) {                         // B for tile t+1 (WAR-safe after issue)
#pragma unroll
      for (int nj = 0; nj < NF; ++nj)
#pragma unroll
        for (int s = 0; s < 4; ++s) RB[nj][s] = *(const bf16x8*)pB(b ^ 1, nj, s);
    }
  }

  u16* smem = (u16*)sc_;
  if constexpr (!OUT_F32) {
    // bf16 epilogue: stage 256x256 tile, coalesced 16B stores, QKV 3-way split
    __builtin_amdgcn_s_barrier();
#pragma unroll
    for (int mi = 0; mi < 4; ++mi)
#pragma unroll
      for (int nj = 0; nj < NF; ++nj) {
        const int colb = wcb + (nj << 5) + l31;
        const float bb = bias[bcol + colb];
#pragma unroll
        for (int r = 0; r < 16; ++r) {
          const int row = (wr << 7) + (mi << 5) + (r & 3) + ((r >> 2) << 3) + (g << 2);
          smem[(row << 8) + colb] = f2bf(acc[mi][nj][r] + bb);
        }
      }
    __syncthreads();
    const int seg = bcol / 768;
    const int cb = bcol - seg * 768;
    u16* dst = (seg == 0) ? dQ : (seg == 1) ? dK : dV;
#pragma unroll
    for (int it = 0; it < 16; ++it) {
      const int f = (it << 9) + tid;
      const int row = f >> 5, c8 = f & 31;
      uint4 v = *(const uint4*)(smem + (row << 8) + (c8 << 3));
      *(uint4*)(dst + (size_t)(brow + row) * 768 + cb + (c8 << 3)) = v;
    }
  } else {
    // f32 epilogue: two 128-row passes via LDS (128 x BN f32)
    float* smf = (float*)sc_;
    __builtin_amdgcn_s_barrier();
#pragma unroll
    for (int p = 0; p < 2; ++p) {
      if (p) __syncthreads();
      if (wr == p) {
#pragma unroll
        for (int mi = 0; mi < 4; ++mi)
#pragma unroll
          for (int nj = 0; nj < NF; ++nj) {
            const int colb = wcb + (nj << 5) + l31;
            const float bb = bias[bcol + colb];
#pragma unroll
            for (int r = 0; r < 16; ++r) {
              const int row = (mi << 5) + (r & 3) + ((r >> 2) << 3) + (g << 2);
              smf[row * BN + colb] = acc[mi][nj][r] + bb;
            }
          }
      }
      __syncthreads();
      constexpr int QPR = BN / 4;
#pragma unroll
      for (int it = 0; it < (128 * QPR) / 512; ++it) {
        const int f = (it << 9) + tid;
        const int row = f / QPR, c4 = f % QPR;
        float4 v = *(const float4*)(smf + row * BN + (c4 << 2));
        *(float4*)(dF + (size_t)(brow + (p << 7) + row) * N + bcol + (c4 << 2)) = v;
      }
    }
  }
}

// ---------------- Window attention: one block per (window, head) ----------------
__global__ __launch_bounds__(256, 4)
void win_attn(const u16* __restrict__ Qg, const u16* __restrict__ Kg,
              const u16* __restrict__ Vg, u16* __restrict__ Og) {
  __shared__ u16 Qs[64 * 72], Ks[64 * 72], Vt[64 * 72], Ps[64 * 72];
  const int cpx = gridDim.x >> 3;
  int bid = blockIdx.x;
  bid = (bid & 7) * cpx + (bid >> 3);
  const int h = bid % HEADS;
  const int gw = bid / HEADS;
  const size_t base = (size_t)gw * WIN * EMBED + (size_t)h * DH;
  const int tid = threadIdx.x;
  const int wid = tid >> 6, lane = tid & 63;

#pragma unroll
  for (int cc = 0; cc < 2; ++cc) {
    const int c = tid + (cc << 8);
    const int row = c >> 3, col8 = c & 7;
    const size_t goff = base + (size_t)row * EMBED + (col8 << 3);
    uint4 q4 = *(const uint4*)(Qg + goff);
    uint4 k4 = *(const uint4*)(Kg + goff);
    uint4 v4 = *(const uint4*)(Vg + goff);
    *(uint4*)(Qs + row * 72 + (col8 << 3)) = q4;
    *(uint4*)(Ks + row * 72 + (col8 << 3)) = k4;
    const u16* vp = (const u16*)&v4;
#pragma unroll
    for (int j = 0; j < 8; ++j)
      Vt[((col8 << 3) + j) * 72 + row] = vp[j];
  }
  __syncthreads();

  f32x4 sacc[4];
#pragma unroll
  for (int t = 0; t < 4; ++t) sacc[t] = (f32x4){0.f, 0.f, 0.f, 0.f};
  const int arow = (wid << 4) + (lane & 15);
  const int kb = ((lane >> 4) << 3);
  bf16x8 qf0 = *(const bf16x8*)(Qs + arow * 72 + kb);
  bf16x8 qf1 = *(const bf16x8*)(Qs + arow * 72 + 32 + kb);
#pragma unroll
  for (int t = 0; t < 4; ++t) {
    const int krow = (t << 4) + (lane & 15);
    bf16x8 kf0 = *(const bf16x8*)(Ks + krow * 72 + kb);
    bf16x8 kf1 = *(const bf16x8*)(Ks + krow * 72 + 32 + kb);
    sacc[t] = __builtin_amdgcn_mfma_f32_16x16x32_bf16(qf0, kf0, sacc[t], 0, 0, 0);
    sacc[t] = __builtin_amdgcn_mfma_f32_16x16x32_bf16(qf1, kf1, sacc[t], 0, 0, 0);
  }

#pragma unroll
  for (int t = 0; t < 4; ++t)
#pragma unroll
    for (int r = 0; r < 4; ++r) sacc[t][r] *= 0.125f;

#pragma unroll
  for (int r = 0; r < 4; ++r) {
    float m0 = fmaxf(fmaxf(sacc[0][r], sacc[1][r]), fmaxf(sacc[2][r], sacc[3][r]));
#pragma unroll
    for (int msk = 1; msk < 16; msk <<= 1) m0 = fmaxf(m0, __shfl_xor(m0, msk));
    float s0 = 0.f;
#pragma unroll
    for (int t = 0; t < 4; ++t) {
      float e = __expf(sacc[t][r] - m0);
      sacc[t][r] = e;
      s0 += e;
    }
#pragma unroll
    for (int msk = 1; msk < 16; msk <<= 1) s0 += __shfl_xor(s0, msk);
    const float inv = 1.f / s0;
#pragma unroll
    for (int t = 0; t < 4; ++t) sacc[t][r] *= inv;
  }

#pragma unroll
  for (int t = 0; t < 4; ++t)
#pragma unroll
    for (int r = 0; r < 4; ++r)
      Ps[((wid << 4) + ((lane >> 4) << 2) + r) * 72 + (t << 4) + (lane & 15)] = f2bf(sacc[t][r]);

  f32x4 oacc[4];
#pragma unroll
  for (int t = 0; t < 4; ++t) oacc[t] = (f32x4){0.f, 0.f, 0.f, 0.f};
  const int prow = (wid << 4) + (lane & 15);
  bf16x8 pf0 = *(const bf16x8*)(Ps + prow * 72 + kb);
  bf16x8 pf1 = *(const bf16x8*)(Ps + prow * 72 + 32 + kb);
#pragma unroll
  for (int t = 0; t < 4; ++t) {
    const int vrow = (t << 4) + (lane & 15);
    bf16x8 vf0 = *(const bf16x8*)(Vt + vrow * 72 + kb);
    bf16x8 vf1 = *(const bf16x8*)(Vt + vrow * 72 + 32 + kb);
    oacc[t] = __builtin_amdgcn_mfma_f32_16x16x32_bf16(pf0, vf0, oacc[t], 0, 0, 0);
    oacc[t] = __builtin_amdgcn_mfma_f32_16x16x32_bf16(pf1, vf1, oacc[t], 0, 0, 0);
  }

#pragma unroll
  for (int t = 0; t < 4; ++t)
#pragma unroll
    for (int r = 0; r < 4; ++r) {
      const int row = (wid << 4) + ((lane >> 4) << 2) + r;
      const int col = (t << 4) + (lane & 15);
      Og[base + (size_t)row * EMBED + col] = f2bf(oacc[t][r]);
    }
}

extern "C" void kernel_launch(void* const* d_in, const int* in_sizes, int n_in,
                              void* d_out, int out_size, void* d_ws, size_t ws_size,
                              hipStream_t stream) {
  const float* q  = (const float*)d_in[0];
  const float* Wq = (const float*)d_in[3];
  const float* bq = (const float*)d_in[4];
  const float* Wk = (const float*)d_in[5];
  const float* bk = (const float*)d_in[6];
  const float* Wv = (const float*)d_in[7];
  const float* bv = (const float*)d_in[8];
  const float* Wo = (const float*)d_in[9];
  const float* bo = (const float*)d_in[10];

  const int C = EMBED;
  const int M = in_sizes[0] / C;                 // 32768
  const size_t xsz = (size_t)M * C;
  const size_t wsz = (size_t)C * C;

  u16* Xb = (u16*)d_out;                         // scratch (overwritten by Wo GEMM)
  u16* Qb = (u16*)d_ws;
  u16* Kb = Qb + xsz;
  u16* Vb = Kb + xsz;
  u16* Wqkv = Vb + xsz;
  u16* Wob = Wqkv + 3 * wsz;
  float* biasc = (float*)(Wob + wsz);

  {
    int n4 = (int)(xsz >> 2);
    cvt_f32_bf16<<<(n4 + 255) / 256, 256, 0, stream>>>(q, Xb, n4);
    int w4 = (int)(wsz >> 2);
    cvt_f32_bf16<<<(w4 + 255) / 256, 256, 0, stream>>>(Wq, Wqkv, w4);
    cvt_f32_bf16<<<(w4 + 255) / 256, 256, 0, stream>>>(Wk, Wqkv + wsz, w4);
    cvt_f32_bf16<<<(w4 + 255) / 256, 256, 0, stream>>>(Wv, Wqkv + 2 * wsz, w4);
    cvt_f32_bf16<<<(w4 + 255) / 256, 256, 0, stream>>>(Wo, Wob, w4);
    concat_bias<<<9, 256, 0, stream>>>(bq, bk, bv, biasc);
  }

  // Fused QKV: [32768 x 2304] = X * Wqkv^T  (grid 1152, %8==0)
  gemm256<4, false><<<(M / 256) * (2304 / 256), 512, 0, stream>>>(
      Xb, Wqkv, biasc, Qb, Kb, Vb, nullptr, 2304);

  win_attn<<<(M / WIN) * HEADS, 256, 0, stream>>>(Qb, Kb, Vb, Qb);

  // Output projection, BN=128: grid 128*6 = 768 = exactly 3 rounds
  gemm256<2, true><<<(M / 256) * (C / 128), 512, 0, stream>>>(
      Qb, Wob, bo, nullptr, nullptr, nullptr, (float*)d_out, C);
}

// Round 7
// 259.461 us; speedup vs baseline: 1.0202x; 1.0202x over previous
//
#include <hip/hip_runtime.h>
#include <hip/hip_bf16.h>

#define EMBED 768
#define HEADS 12
#define WIN 64
#define DH 64
#define KDIM 768
#define NTILE 12      // KDIM / 64

typedef unsigned short u16;
typedef unsigned int u32;
typedef __attribute__((ext_vector_type(8))) short bf16x8;
typedef __attribute__((ext_vector_type(4))) float f32x4;

__device__ __forceinline__ u16 f2bf(float f) {
  union { float f; u32 u; } x; x.f = f;
  return (u16)((x.u + 0x7fffu + ((x.u >> 16) & 1u)) >> 16);
}

// ---------------- fp32 -> bf16 convert ----------------
__global__ void cvt_f32_bf16(const float* __restrict__ in, u16* __restrict__ out, int n4) {
  int i = blockIdx.x * blockDim.x + threadIdx.x;
  if (i >= n4) return;
  float4 v = ((const float4*)in)[i];
  ushort4 o;
  o.x = f2bf(v.x); o.y = f2bf(v.y); o.z = f2bf(v.z); o.w = f2bf(v.w);
  ((ushort4*)out)[i] = o;
}

__global__ void concat_bias(const float* __restrict__ bq, const float* __restrict__ bk,
                            const float* __restrict__ bv, float* __restrict__ out) {
  int i = blockIdx.x * 256 + threadIdx.x;
  if (i < 768) out[i] = bq[i];
  else if (i < 1536) out[i] = bk[i - 768];
  else if (i < 2304) out[i] = bv[i - 1536];
}

// ---------------- 256xBN NT GEMM, m201-style per-phase interleave ----------------
// BM=256, BN=BNW*64, BK=64, 512 thr = 8 waves (2M x 4N); per-wave 128 x BNW*16.
// Per K-tile: 4 phases (C-quadrants). Each phase: {4 A ds_reads (+all B at q0),
// 2 global_load_lds quarters of tile t+1 into the other buf, s_barrier,
// lgkmcnt(0), setprio(1), 16 MFMA, setprio(0), s_barrier}. vmcnt(0) once per
// tile at q3 (stages ~800cyc old). T1 XCD swizzle, T2 XOR-LDS swizzle.
template<int BNW, bool OUT_F32>
__global__ __launch_bounds__(512, 1)
void gemm256(const u16* __restrict__ A, const u16* __restrict__ Bw,
             const float* __restrict__ bias,
             u16* __restrict__ dQ, u16* __restrict__ dK, u16* __restrict__ dV,
             float* __restrict__ dF, int N) {
  constexpr int BN = BNW * 64;
  constexpr int BBUF = BNW * 8192;               // bytes per B K-tile buf
  __shared__ char sc_[65536 + 2 * BBUF];
  const int tid = threadIdx.x;
  const int lane = tid & 63;
  const int wid = tid >> 6;
  const int wr = wid >> 2, wc = wid & 3;
  const int l15 = lane & 15;

  const int nbx = N / BN;
  const int cpx = gridDim.x >> 3;
  int bid = blockIdx.x;
  bid = (bid & 7) * cpx + (bid >> 3);            // bijective: grid % 8 == 0
  const int brow = (bid / nbx) << 8;
  const int bcol = (bid % nbx) * BN;

  // staging source (per-thread), pre-swizzled global col (T2, rule 21)
  const int srow = tid >> 3;
  const int scol = ((tid & 7) ^ (srow & 7)) << 3;
  const u16* Asrc = A + (size_t)(brow + srow) * KDIM + scol;
  const u16* Bsrc = Bw + (size_t)(bcol + srow) * KDIM + scol;
  const int lds_woff = wid << 10;

  // stage one 64-row "quarter" (1 gload/thread = 8KB)
  auto STAGE_A = [&](int b, int i, int kt) {
    __builtin_amdgcn_global_load_lds(
        (const __attribute__((address_space(1))) void*)(Asrc + (size_t)(i << 6) * KDIM + kt),
        (__attribute__((address_space(3))) void*)(sc_ + b * 32768 + (i << 13) + lds_woff), 16, 0, 0);
  };
  auto STAGE_B = [&](int b, int i, int kt) {
    __builtin_amdgcn_global_load_lds(
        (const __attribute__((address_space(1))) void*)(Bsrc + (size_t)(i << 6) * KDIM + kt),
        (__attribute__((address_space(3))) void*)(sc_ + 65536 + b * BBUF + (i << 13) + lds_woff), 16, 0, 0);
  };

  // frag-read byte offsets: row*128 + ((kk*4 + (lane>>4))^ (row&7))*16; row&7 == l15&7
  const int swz = (l15 & 7) << 4;
  const int cb0 = (((lane >> 4) << 4)) ^ swz;          // kk=0
  const int cb1 = ((((lane >> 4) + 4) << 4)) ^ swz;    // kk=1
  auto pA = [&](int b, int mi) -> const char* {
    return sc_ + b * 32768 + ((wr << 7) + (mi << 4) + l15) * 128;
  };
  auto pB = [&](int b, int nj) -> const char* {
    return sc_ + 65536 + b * BBUF + (wc * (BNW << 4) + (nj << 4) + l15) * 128;
  };

  f32x4 acc[8][BNW];
#pragma unroll
  for (int m = 0; m < 8; ++m)
#pragma unroll
    for (int n = 0; n < BNW; ++n) acc[m][n] = (f32x4){0.f, 0.f, 0.f, 0.f};

  bf16x8 RB[BNW][2];

  // ---- prologue: stage tile 0 fully, drain, barrier ----
#pragma unroll
  for (int i = 0; i < 4; ++i) STAGE_A(0, i, 0);
#pragma unroll
  for (int i = 0; i < BNW; ++i) STAGE_B(0, i, 0);
  asm volatile("s_waitcnt vmcnt(0)" ::: "memory");
  __builtin_amdgcn_sched_barrier(0);
  __builtin_amdgcn_s_barrier();

#pragma unroll 2
  for (int t = 0; t < NTILE; ++t) {
    const int b = t & 1;
    const bool st = (t + 1 < NTILE);
    const int kn = (t + 1) << 6;
#pragma unroll
    for (int q = 0; q < 4; ++q) {
      // ---- ds_reads for this phase ----
      if (q == 0) {
#pragma unroll
        for (int nj = 0; nj < BNW; ++nj) {
          RB[nj][0] = *(const bf16x8*)(pB(b, nj) + cb0);
          RB[nj][1] = *(const bf16x8*)(pB(b, nj) + cb1);
        }
      }
      bf16x8 ra[2][2];
#pragma unroll
      for (int m = 0; m < 2; ++m) {
        ra[m][0] = *(const bf16x8*)(pA(b, 2 * q + m) + cb0);
        ra[m][1] = *(const bf16x8*)(pA(b, 2 * q + m) + cb1);
      }
      // ---- stage 2 quarters of tile t+1 into the other buf ----
      if (st) {
        if (BNW == 4) {
          if (q == 0) { STAGE_A(b ^ 1, 0, kn); STAGE_A(b ^ 1, 1, kn); }
          else if (q == 1) { STAGE_A(b ^ 1, 2, kn); STAGE_A(b ^ 1, 3, kn); }
          else if (q == 2) { STAGE_B(b ^ 1, 0, kn); STAGE_B(b ^ 1, 1, kn); }
          else { STAGE_B(b ^ 1, 2, kn); STAGE_B(b ^ 1, 3, kn); }
        } else {
          if (q == 0) { STAGE_A(b ^ 1, 0, kn); STAGE_A(b ^ 1, 1, kn); }
          else if (q == 1) { STAGE_A(b ^ 1, 2, kn); STAGE_A(b ^ 1, 3, kn); }
          else if (q == 2) { STAGE_B(b ^ 1, 0, kn); STAGE_B(b ^ 1, 1, kn); }
        }
      }
      // ---- phase-locked compute ----
      __builtin_amdgcn_s_barrier();
      asm volatile("s_waitcnt lgkmcnt(0)" ::: "memory");
      __builtin_amdgcn_sched_barrier(0);
      __builtin_amdgcn_s_setprio(1);
#pragma unroll
      for (int nj = 0; nj < BNW; ++nj) {
        acc[2 * q][nj]     = __builtin_amdgcn_mfma_f32_16x16x32_bf16(ra[0][0], RB[nj][0], acc[2 * q][nj], 0, 0, 0);
        acc[2 * q][nj]     = __builtin_amdgcn_mfma_f32_16x16x32_bf16(ra[0][1], RB[nj][1], acc[2 * q][nj], 0, 0, 0);
        acc[2 * q + 1][nj] = __builtin_amdgcn_mfma_f32_16x16x32_bf16(ra[1][0], RB[nj][0], acc[2 * q + 1][nj], 0, 0, 0);
        acc[2 * q + 1][nj] = __builtin_amdgcn_mfma_f32_16x16x32_bf16(ra[1][1], RB[nj][1], acc[2 * q + 1][nj], 0, 0, 0);
      }
      __builtin_amdgcn_s_setprio(0);
      if (q == 3 && st) {                        // stages ~800cyc old here
        asm volatile("s_waitcnt vmcnt(0)" ::: "memory");
        __builtin_amdgcn_sched_barrier(0);
      }
      __builtin_amdgcn_s_barrier();
    }
  }

  u16* smem = (u16*)sc_;
  if constexpr (!OUT_F32) {
    // bf16 epilogue: stage 256x256 tile, coalesced 16B stores, QKV 3-way split
#pragma unroll
    for (int mi = 0; mi < 8; ++mi)
#pragma unroll
      for (int nj = 0; nj < BNW; ++nj) {
        const int colb = (wc << 6) + (nj << 4) + l15;
        const float bb = bias[bcol + colb];
        const int row0 = (wr << 7) + (mi << 4) + ((lane >> 4) << 2);
#pragma unroll
        for (int rr = 0; rr < 4; ++rr)
          smem[((row0 + rr) << 8) + colb] = f2bf(acc[mi][nj][rr] + bb);
      }
    __syncthreads();
    const int seg = bcol / 768;
    const int cb = bcol - seg * 768;
    u16* dst = (seg == 0) ? dQ : (seg == 1) ? dK : dV;
#pragma unroll
    for (int it = 0; it < 16; ++it) {
      const int f = (it << 9) + tid;
      const int row = f >> 5, c8 = f & 31;
      uint4 v = *(const uint4*)(smem + (row << 8) + (c8 << 3));
      *(uint4*)(dst + (size_t)(brow + row) * 768 + cb + (c8 << 3)) = v;
    }
  } else {
    // f32 epilogue: two 128-row passes via LDS (128 x BN f32)
    float* smf = (float*)sc_;
#pragma unroll
    for (int p = 0; p < 2; ++p) {
      if (p) __syncthreads();
      if (wr == p) {
#pragma unroll
        for (int mi = 0; mi < 8; ++mi)
#pragma unroll
          for (int nj = 0; nj < BNW; ++nj) {
            const int colb = wc * (BNW << 4) + (nj << 4) + l15;
            const float bb = bias[bcol + colb];
            const int row0 = (mi << 4) + ((lane >> 4) << 2);
#pragma unroll
            for (int rr = 0; rr < 4; ++rr)
              smf[(row0 + rr) * BN + colb] = acc[mi][nj][rr] + bb;
          }
      }
      __syncthreads();
      constexpr int QPR = BN / 4;
#pragma unroll
      for (int it = 0; it < (128 * QPR) / 512; ++it) {
        const int f = (it << 9) + tid;
        const int row = f / QPR, c4 = f % QPR;
        float4 v = *(const float4*)(smf + row * BN + (c4 << 2));
        *(float4*)(dF + (size_t)(brow + (p << 7) + row) * N + bcol + (c4 << 2)) = v;
      }
    }
  }
}

// ---------------- Window attention: one block per (window, head) ----------------
__global__ __launch_bounds__(256, 4)
void win_attn(const u16* __restrict__ Qg, const u16* __restrict__ Kg,
              const u16* __restrict__ Vg, u16* __restrict__ Og) {
  __shared__ u16 Qs[64 * 72], Ks[64 * 72], Vt[64 * 72], Ps[64 * 72];
  const int cpx = gridDim.x >> 3;
  int bid = blockIdx.x;
  bid = (bid & 7) * cpx + (bid >> 3);
  const int h = bid % HEADS;
  const int gw = bid / HEADS;
  const size_t base = (size_t)gw * WIN * EMBED + (size_t)h * DH;
  const int tid = threadIdx.x;
  const int wid = tid >> 6, lane = tid & 63;

#pragma unroll
  for (int cc = 0; cc < 2; ++cc) {
    const int c = tid + (cc << 8);
    const int row = c >> 3, col8 = c & 7;
    const size_t goff = base + (size_t)row * EMBED + (col8 << 3);
    uint4 q4 = *(const uint4*)(Qg + goff);
    uint4 k4 = *(const uint4*)(Kg + goff);
    uint4 v4 = *(const uint4*)(Vg + goff);
    *(uint4*)(Qs + row * 72 + (col8 << 3)) = q4;
    *(uint4*)(Ks + row * 72 + (col8 << 3)) = k4;
    const u16* vp = (const u16*)&v4;
#pragma unroll
    for (int j = 0; j < 8; ++j)
      Vt[((col8 << 3) + j) * 72 + row] = vp[j];
  }
  __syncthreads();

  f32x4 sacc[4];
#pragma unroll
  for (int t = 0; t < 4; ++t) sacc[t] = (f32x4){0.f, 0.f, 0.f, 0.f};
  const int arow = (wid << 4) + (lane & 15);
  const int kb = ((lane >> 4) << 3);
  bf16x8 qf0 = *(const bf16x8*)(Qs + arow * 72 + kb);
  bf16x8 qf1 = *(const bf16x8*)(Qs + arow * 72 + 32 + kb);
#pragma unroll
  for (int t = 0; t < 4; ++t) {
    const int krow = (t << 4) + (lane & 15);
    bf16x8 kf0 = *(const bf16x8*)(Ks + krow * 72 + kb);
    bf16x8 kf1 = *(const bf16x8*)(Ks + krow * 72 + 32 + kb);
    sacc[t] = __builtin_amdgcn_mfma_f32_16x16x32_bf16(qf0, kf0, sacc[t], 0, 0, 0);
    sacc[t] = __builtin_amdgcn_mfma_f32_16x16x32_bf16(qf1, kf1, sacc[t], 0, 0, 0);
  }

#pragma unroll
  for (int t = 0; t < 4; ++t)
#pragma unroll
    for (int r = 0; r < 4; ++r) sacc[t][r] *= 0.125f;

#pragma unroll
  for (int r = 0; r < 4; ++r) {
    float m0 = fmaxf(fmaxf(sacc[0][r], sacc[1][r]), fmaxf(sacc[2][r], sacc[3][r]));
#pragma unroll
    for (int msk = 1; msk < 16; msk <<= 1) m0 = fmaxf(m0, __shfl_xor(m0, msk));
    float s0 = 0.f;
#pragma unroll
    for (int t = 0; t < 4; ++t) {
      float e = __expf(sacc[t][r] - m0);
      sacc[t][r] = e;
      s0 += e;
    }
#pragma unroll
    for (int msk = 1; msk < 16; msk <<= 1) s0 += __shfl_xor(s0, msk);
    const float inv = 1.f / s0;
#pragma unroll
    for (int t = 0; t < 4; ++t) sacc[t][r] *= inv;
  }

#pragma unroll
  for (int t = 0; t < 4; ++t)
#pragma unroll
    for (int r = 0; r < 4; ++r)
      Ps[((wid << 4) + ((lane >> 4) << 2) + r) * 72 + (t << 4) + (lane & 15)] = f2bf(sacc[t][r]);

  f32x4 oacc[4];
#pragma unroll
  for (int t = 0; t < 4; ++t) oacc[t] = (f32x4){0.f, 0.f, 0.f, 0.f};
  const int prow = (wid << 4) + (lane & 15);
  bf16x8 pf0 = *(const bf16x8*)(Ps + prow * 72 + kb);
  bf16x8 pf1 = *(const bf16x8*)(Ps + prow * 72 + 32 + kb);
#pragma unroll
  for (int t = 0; t < 4; ++t) {
    const int vrow = (t << 4) + (lane & 15);
    bf16x8 vf0 = *(const bf16x8*)(Vt + vrow * 72 + kb);
    bf16x8 vf1 = *(const bf16x8*)(Vt + vrow * 72 + 32 + kb);
    oacc[t] = __builtin_amdgcn_mfma_f32_16x16x32_bf16(pf0, vf0, oacc[t], 0, 0, 0);
    oacc[t] = __builtin_amdgcn_mfma_f32_16x16x32_bf16(pf1, vf1, oacc[t], 0, 0, 0);
  }

#pragma unroll
  for (int t = 0; t < 4; ++t)
#pragma unroll
    for (int r = 0; r < 4; ++r) {
      const int row = (wid << 4) + ((lane >> 4) << 2) + r;
      const int col = (t << 4) + (lane & 15);
      Og[base + (size_t)row * EMBED + col] = f2bf(oacc[t][r]);
    }
}

extern "C" void kernel_launch(void* const* d_in, const int* in_sizes, int n_in,
                              void* d_out, int out_size, void* d_ws, size_t ws_size,
                              hipStream_t stream) {
  const float* q  = (const float*)d_in[0];
  const float* Wq = (const float*)d_in[3];
  const float* bq = (const float*)d_in[4];
  const float* Wk = (const float*)d_in[5];
  const float* bk = (const float*)d_in[6];
  const float* Wv = (const float*)d_in[7];
  const float* bv = (const float*)d_in[8];
  const float* Wo = (const float*)d_in[9];
  const float* bo = (const float*)d_in[10];

  const int C = EMBED;
  const int M = in_sizes[0] / C;                 // 32768
  const size_t xsz = (size_t)M * C;
  const size_t wsz = (size_t)C * C;

  u16* Xb = (u16*)d_out;                         // scratch (overwritten by Wo GEMM)
  u16* Qb = (u16*)d_ws;
  u16* Kb = Qb + xsz;
  u16* Vb = Kb + xsz;
  u16* Wqkv = Vb + xsz;
  u16* Wob = Wqkv + 3 * wsz;
  float* biasc = (float*)(Wob + wsz);

  {
    int n4 = (int)(xsz >> 2);
    cvt_f32_bf16<<<(n4 + 255) / 256, 256, 0, stream>>>(q, Xb, n4);
    int w4 = (int)(wsz >> 2);
    cvt_f32_bf16<<<(w4 + 255) / 256, 256, 0, stream>>>(Wq, Wqkv, w4);
    cvt_f32_bf16<<<(w4 + 255) / 256, 256, 0, stream>>>(Wk, Wqkv + wsz, w4);
    cvt_f32_bf16<<<(w4 + 255) / 256, 256, 0, stream>>>(Wv, Wqkv + 2 * wsz, w4);
    cvt_f32_bf16<<<(w4 + 255) / 256, 256, 0, stream>>>(Wo, Wob, w4);
    concat_bias<<<9, 256, 0, stream>>>(bq, bk, bv, biasc);
  }

  // Fused QKV: [32768 x 2304] = X * Wqkv^T  (grid 1152, %8==0)
  gemm256<4, false><<<(M / 256) * (2304 / 256), 512, 0, stream>>>(
      Xb, Wqkv, biasc, Qb, Kb, Vb, nullptr, 2304);

  win_attn<<<(M / WIN) * HEADS, 256, 0, stream>>>(Qb, Kb, Vb, Qb);

  // Output projection, BN=128: grid 128*6 = 768 = exactly 3 rounds
  gemm256<2, true><<<(M / 256) * (C / 128), 512, 0, stream>>>(
      Qb, Wob, bo, nullptr, nullptr, nullptr, (float*)d_out, C);
}

// Round 8
// 254.617 us; speedup vs baseline: 1.0396x; 1.0190x over previous
//
#include <hip/hip_runtime.h>
#include <hip/hip_bf16.h>

#define EMBED 768
#define HEADS 12
#define WIN 64
#define DH 64
#define KDIM 768
#define NTILE 12      // KDIM / 64

typedef unsigned short u16;
typedef unsigned int u32;
typedef __attribute__((ext_vector_type(8))) short bf16x8;
typedef __attribute__((ext_vector_type(4))) float f32x4;

__device__ __forceinline__ u16 f2bf(float f) {
  union { float f; u32 u; } x; x.f = f;
  return (u16)((x.u + 0x7fffu + ((x.u >> 16) & 1u)) >> 16);
}

// ---------------- fp32 -> bf16 convert ----------------
__global__ void cvt_f32_bf16(const float* __restrict__ in, u16* __restrict__ out, int n4) {
  int i = blockIdx.x * blockDim.x + threadIdx.x;
  if (i >= n4) return;
  float4 v = ((const float4*)in)[i];
  ushort4 o;
  o.x = f2bf(v.x); o.y = f2bf(v.y); o.z = f2bf(v.z); o.w = f2bf(v.w);
  ((ushort4*)out)[i] = o;
}

// Per-head-interleaved QKV weights: out row r = h*192 + {0-63:Wq, 64-127:Wk, 128-191:Wv}[h*64+d]
__global__ void cvt_wqkv(const float* __restrict__ Wq, const float* __restrict__ Wk,
                         const float* __restrict__ Wv, const float* __restrict__ bq,
                         const float* __restrict__ bk, const float* __restrict__ bv,
                         u16* __restrict__ Wp, float* __restrict__ bp) {
  int i = blockIdx.x * 256 + threadIdx.x;        // one float4 each
  if (i >= 2304 * 192) return;
  int r = i / 192, c4 = i % 192;
  int h = r / 192, t = (r % 192) / 64, d = r % 64;
  const float* W = (t == 0) ? Wq : (t == 1) ? Wk : Wv;
  float4 v = *(const float4*)(W + (size_t)(h * 64 + d) * 768 + c4 * 4);
  ushort4 o;
  o.x = f2bf(v.x); o.y = f2bf(v.y); o.z = f2bf(v.z); o.w = f2bf(v.w);
  *(ushort4*)(Wp + (size_t)r * 768 + c4 * 4) = o;
  if (c4 == 0) {
    const float* bb = (t == 0) ? bq : (t == 1) ? bk : bv;
    bp[r] = bb[h * 64 + d];
  }
}

// ---------------- Fused QKV-projection + window attention ----------------
// Block = 256 rows (4 windows) x 192 cols (head h's Q|K|V), K=768.
// Main loop: 4-phase m201-style interleave (12 MFMA/phase). Epilogue: scatter
// acc -> LDS {Q,K row-major stride-72; V transposed}, per-window attention
// (2 waves/window: MFMA QK^T, 16-lane shfl softmax, MFMA PV), coalesced O out.
__global__ __launch_bounds__(512, 1)
void qkva(const u16* __restrict__ A, const u16* __restrict__ Bw,
          const float* __restrict__ biasp, u16* __restrict__ O) {
  __shared__ char sc_[114688];                   // staging 112KB / attn 108KB
  const int tid = threadIdx.x;
  const int lane = tid & 63;
  const int wid = tid >> 6;
  const int wr = wid >> 2, wc = wid & 3;
  const int l15 = lane & 15;

  const int cpx = gridDim.x >> 3;
  int bid = blockIdx.x;
  bid = (bid & 7) * cpx + (bid >> 3);            // grid 1536 % 8 == 0
  const int head = bid % HEADS;
  const int brow = (bid / HEADS) << 8;
  const int bcolw = head * 192;                  // row base into Wp

  const int srow = tid >> 3;
  const int scol = ((tid & 7) ^ (srow & 7)) << 3;   // T2 pre-swizzled source
  const u16* Asrc = A + (size_t)(brow + srow) * KDIM + scol;
  const u16* Bsrc = Bw + (size_t)(bcolw + srow) * KDIM + scol;
  const int lds_woff = wid << 10;

  auto STAGE_A = [&](int b, int i, int kt) {
    __builtin_amdgcn_global_load_lds(
        (const __attribute__((address_space(1))) void*)(Asrc + (size_t)(i << 6) * KDIM + kt),
        (__attribute__((address_space(3))) void*)(sc_ + b * 32768 + (i << 13) + lds_woff), 16, 0, 0);
  };
  auto STAGE_B = [&](int b, int i, int kt) {
    __builtin_amdgcn_global_load_lds(
        (const __attribute__((address_space(1))) void*)(Bsrc + (size_t)(i << 6) * KDIM + kt),
        (__attribute__((address_space(3))) void*)(sc_ + 65536 + b * 24576 + (i << 13) + lds_woff), 16, 0, 0);
  };

  const int swz = (l15 & 7) << 4;
  const int cb0 = ((lane >> 4) << 4) ^ swz;
  const int cb1 = (((lane >> 4) + 4) << 4) ^ swz;
  auto pA = [&](int b, int mi) -> const char* {
    return sc_ + b * 32768 + ((wr << 7) + (mi << 4) + l15) * 128;
  };
  auto pB = [&](int b, int nj) -> const char* {
    return sc_ + 65536 + b * 24576 + (wc * 48 + (nj << 4) + l15) * 128;
  };

  f32x4 acc[8][3];
#pragma unroll
  for (int m = 0; m < 8; ++m)
#pragma unroll
    for (int n = 0; n < 3; ++n) acc[m][n] = (f32x4){0.f, 0.f, 0.f, 0.f};
  bf16x8 RB[3][2];

  // prologue
#pragma unroll
  for (int i = 0; i < 4; ++i) STAGE_A(0, i, 0);
#pragma unroll
  for (int i = 0; i < 3; ++i) STAGE_B(0, i, 0);
  asm volatile("s_waitcnt vmcnt(0)" ::: "memory");
  __builtin_amdgcn_sched_barrier(0);
  __builtin_amdgcn_s_barrier();

#pragma unroll 2
  for (int t = 0; t < NTILE; ++t) {
    const int b = t & 1;
    const bool st = (t + 1 < NTILE);
    const int kn = (t + 1) << 6;
#pragma unroll
    for (int q = 0; q < 4; ++q) {
      if (q == 0) {
#pragma unroll
        for (int nj = 0; nj < 3; ++nj) {
          RB[nj][0] = *(const bf16x8*)(pB(b, nj) + cb0);
          RB[nj][1] = *(const bf16x8*)(pB(b, nj) + cb1);
        }
      }
      bf16x8 ra[2][2];
#pragma unroll
      for (int m = 0; m < 2; ++m) {
        ra[m][0] = *(const bf16x8*)(pA(b, 2 * q + m) + cb0);
        ra[m][1] = *(const bf16x8*)(pA(b, 2 * q + m) + cb1);
      }
      if (st) {
        if (q == 0) { STAGE_A(b ^ 1, 0, kn); STAGE_A(b ^ 1, 1, kn); }
        else if (q == 1) { STAGE_A(b ^ 1, 2, kn); STAGE_A(b ^ 1, 3, kn); }
        else if (q == 2) { STAGE_B(b ^ 1, 0, kn); STAGE_B(b ^ 1, 1, kn); }
        else { STAGE_B(b ^ 1, 2, kn); }
      }
      __builtin_amdgcn_s_barrier();
      asm volatile("s_waitcnt lgkmcnt(0)" ::: "memory");
      __builtin_amdgcn_sched_barrier(0);
      __builtin_amdgcn_s_setprio(1);
#pragma unroll
      for (int nj = 0; nj < 3; ++nj) {
        acc[2 * q][nj]     = __builtin_amdgcn_mfma_f32_16x16x32_bf16(ra[0][0], RB[nj][0], acc[2 * q][nj], 0, 0, 0);
        acc[2 * q][nj]     = __builtin_amdgcn_mfma_f32_16x16x32_bf16(ra[0][1], RB[nj][1], acc[2 * q][nj], 0, 0, 0);
        acc[2 * q + 1][nj] = __builtin_amdgcn_mfma_f32_16x16x32_bf16(ra[1][0], RB[nj][0], acc[2 * q + 1][nj], 0, 0, 0);
        acc[2 * q + 1][nj] = __builtin_amdgcn_mfma_f32_16x16x32_bf16(ra[1][1], RB[nj][1], acc[2 * q + 1][nj], 0, 0, 0);
      }
      __builtin_amdgcn_s_setprio(0);
      if (q == 3 && st) {
        asm volatile("s_waitcnt vmcnt(0)" ::: "memory");
        __builtin_amdgcn_sched_barrier(0);
      }
      __builtin_amdgcn_s_barrier();
    }
  }

  // ---- epilogue: scatter Q,K (row-major) and V (transposed) into attn LDS ----
  u16* qp  = (u16*)sc_;                          // [4][64][72]  Q, later P
  u16* kk_ = (u16*)(sc_ + 36864);                // [4][64][72]  K, later O
  u16* vv  = (u16*)(sc_ + 73728);                // [4][64][72]  V^T (d-major)
#pragma unroll
  for (int mi = 0; mi < 8; ++mi) {
    const int row0 = (wr << 7) + (mi << 4) + ((lane >> 4) << 2);
#pragma unroll
    for (int nj = 0; nj < 3; ++nj) {
      const int col = wc * 48 + (nj << 4) + l15;
      const float bb = biasp[bcolw + col];
#pragma unroll
      for (int rr = 0; rr < 4; ++rr) {
        const int rw = row0 + rr;
        const int win = rw >> 6, rloc = rw & 63;
        const u16 val = f2bf(acc[mi][nj][rr] + bb);
        if (col < 64)       qp [win * 4608 + rloc * 72 + col] = val;
        else if (col < 128) kk_[win * 4608 + rloc * 72 + (col - 64)] = val;
        else                vv [win * 4608 + (col - 128) * 72 + rloc] = val;
      }
    }
  }
  __syncthreads();

  // ---- attention: wave pair per window; this wave owns rows [half*32, +32) ----
  const int w = wid >> 1, half = wid & 1;
  u16* qw = qp + w * 4608;
  u16* kw = kk_ + w * 4608;
  u16* vw = vv + w * 4608;
  const int g8 = (lane >> 4) << 3;
  const int g4 = (lane >> 4) << 2;

  f32x4 sacc[2][4];
#pragma unroll
  for (int m = 0; m < 2; ++m)
#pragma unroll
    for (int t = 0; t < 4; ++t) sacc[m][t] = (f32x4){0.f, 0.f, 0.f, 0.f};
  bf16x8 aq[2][2];
#pragma unroll
  for (int m = 0; m < 2; ++m) {
    const int r = half * 32 + m * 16 + l15;
    aq[m][0] = *(const bf16x8*)(qw + r * 72 + g8);
    aq[m][1] = *(const bf16x8*)(qw + r * 72 + 32 + g8);
  }
#pragma unroll
  for (int t = 0; t < 4; ++t) {
    const int kr = t * 16 + l15;
    bf16x8 bk0 = *(const bf16x8*)(kw + kr * 72 + g8);
    bf16x8 bk1 = *(const bf16x8*)(kw + kr * 72 + 32 + g8);
#pragma unroll
    for (int m = 0; m < 2; ++m) {
      sacc[m][t] = __builtin_amdgcn_mfma_f32_16x16x32_bf16(aq[m][0], bk0, sacc[m][t], 0, 0, 0);
      sacc[m][t] = __builtin_amdgcn_mfma_f32_16x16x32_bf16(aq[m][1], bk1, sacc[m][t], 0, 0, 0);
    }
  }
#pragma unroll
  for (int m = 0; m < 2; ++m)
#pragma unroll
    for (int t = 0; t < 4; ++t)
#pragma unroll
      for (int r = 0; r < 4; ++r) sacc[m][t][r] *= 0.125f;

#pragma unroll
  for (int m = 0; m < 2; ++m)
#pragma unroll
    for (int r = 0; r < 4; ++r) {
      float m0 = fmaxf(fmaxf(sacc[m][0][r], sacc[m][1][r]), fmaxf(sacc[m][2][r], sacc[m][3][r]));
#pragma unroll
      for (int msk = 1; msk < 16; msk <<= 1) m0 = fmaxf(m0, __shfl_xor(m0, msk));
      float s0 = 0.f;
#pragma unroll
      for (int t = 0; t < 4; ++t) {
        float e = __expf(sacc[m][t][r] - m0);
        sacc[m][t][r] = e;
        s0 += e;
      }
#pragma unroll
      for (int msk = 1; msk < 16; msk <<= 1) s0 += __shfl_xor(s0, msk);
      const float inv = 1.f / s0;
#pragma unroll
      for (int t = 0; t < 4; ++t) sacc[m][t][r] *= inv;
    }

  // P -> qw (Q dead; rows disjoint between wave pair)
#pragma unroll
  for (int m = 0; m < 2; ++m)
#pragma unroll
    for (int t = 0; t < 4; ++t)
#pragma unroll
      for (int r = 0; r < 4; ++r)
        qw[(half * 32 + m * 16 + g4 + r) * 72 + t * 16 + l15] = f2bf(sacc[m][t][r]);

  // PV
  f32x4 oacc[2][4];
#pragma unroll
  for (int m = 0; m < 2; ++m)
#pragma unroll
    for (int t = 0; t < 4; ++t) oacc[m][t] = (f32x4){0.f, 0.f, 0.f, 0.f};
  bf16x8 ap[2][2];
#pragma unroll
  for (int m = 0; m < 2; ++m) {
    const int r = half * 32 + m * 16 + l15;
    ap[m][0] = *(const bf16x8*)(qw + r * 72 + g8);
    ap[m][1] = *(const bf16x8*)(qw + r * 72 + 32 + g8);
  }
#pragma unroll
  for (int t = 0; t < 4; ++t) {
    const int dr = t * 16 + l15;
    bf16x8 bv0 = *(const bf16x8*)(vw + dr * 72 + g8);
    bf16x8 bv1 = *(const bf16x8*)(vw + dr * 72 + 32 + g8);
#pragma unroll
    for (int m = 0; m < 2; ++m) {
      oacc[m][t] = __builtin_amdgcn_mfma_f32_16x16x32_bf16(ap[m][0], bv0, oacc[m][t], 0, 0, 0);
      oacc[m][t] = __builtin_amdgcn_mfma_f32_16x16x32_bf16(ap[m][1], bv1, oacc[m][t], 0, 0, 0);
    }
  }
  __syncthreads();                               // K area dead for all waves
#pragma unroll
  for (int m = 0; m < 2; ++m)
#pragma unroll
    for (int t = 0; t < 4; ++t)
#pragma unroll
      for (int r = 0; r < 4; ++r)
        kw[(half * 32 + m * 16 + g4 + r) * 72 + t * 16 + l15] = f2bf(oacc[m][t][r]);
  __syncthreads();

  // coalesced O store: 256 rows x 128B
#pragma unroll
  for (int it = 0; it < 4; ++it) {
    const int f = (it << 9) + tid;
    const int row = f >> 3, c8 = f & 7;
    uint4 v = *(const uint4*)(kk_ + (row >> 6) * 4608 + (row & 63) * 72 + (c8 << 3));
    *(uint4*)(O + (size_t)(brow + row) * 768 + head * 64 + (c8 << 3)) = v;
  }
}

// ---------------- 256xBN NT GEMM (Wo projection), unchanged ----------------
template<int BNW, bool OUT_F32>
__global__ __launch_bounds__(512, 1)
void gemm256(const u16* __restrict__ A, const u16* __restrict__ Bw,
             const float* __restrict__ bias,
             u16* __restrict__ dQ, u16* __restrict__ dK, u16* __restrict__ dV,
             float* __restrict__ dF, int N) {
  constexpr int BN = BNW * 64;
  constexpr int BBUF = BNW * 8192;
  __shared__ char sc_[65536 + 2 * BBUF];
  const int tid = threadIdx.x;
  const int lane = tid & 63;
  const int wid = tid >> 6;
  const int wr = wid >> 2, wc = wid & 3;
  const int l15 = lane & 15;

  const int nbx = N / BN;
  const int cpx = gridDim.x >> 3;
  int bid = blockIdx.x;
  bid = (bid & 7) * cpx + (bid >> 3);
  const int brow = (bid / nbx) << 8;
  const int bcol = (bid % nbx) * BN;

  const int srow = tid >> 3;
  const int scol = ((tid & 7) ^ (srow & 7)) << 3;
  const u16* Asrc = A + (size_t)(brow + srow) * KDIM + scol;
  const u16* Bsrc = Bw + (size_t)(bcol + srow) * KDIM + scol;
  const int lds_woff = wid << 10;

  auto STAGE_A = [&](int b, int i, int kt) {
    __builtin_amdgcn_global_load_lds(
        (const __attribute__((address_space(1))) void*)(Asrc + (size_t)(i << 6) * KDIM + kt),
        (__attribute__((address_space(3))) void*)(sc_ + b * 32768 + (i << 13) + lds_woff), 16, 0, 0);
  };
  auto STAGE_B = [&](int b, int i, int kt) {
    __builtin_amdgcn_global_load_lds(
        (const __attribute__((address_space(1))) void*)(Bsrc + (size_t)(i << 6) * KDIM + kt),
        (__attribute__((address_space(3))) void*)(sc_ + 65536 + b * BBUF + (i << 13) + lds_woff), 16, 0, 0);
  };

  const int swz = (l15 & 7) << 4;
  const int cb0 = ((lane >> 4) << 4) ^ swz;
  const int cb1 = (((lane >> 4) + 4) << 4) ^ swz;
  auto pA = [&](int b, int mi) -> const char* {
    return sc_ + b * 32768 + ((wr << 7) + (mi << 4) + l15) * 128;
  };
  auto pB = [&](int b, int nj) -> const char* {
    return sc_ + 65536 + b * BBUF + (wc * (BNW << 4) + (nj << 4) + l15) * 128;
  };

  f32x4 acc[8][BNW];
#pragma unroll
  for (int m = 0; m < 8; ++m)
#pragma unroll
    for (int n = 0; n < BNW; ++n) acc[m][n] = (f32x4){0.f, 0.f, 0.f, 0.f};
  bf16x8 RB[BNW][2];

#pragma unroll
  for (int i = 0; i < 4; ++i) STAGE_A(0, i, 0);
#pragma unroll
  for (int i = 0; i < BNW; ++i) STAGE_B(0, i, 0);
  asm volatile("s_waitcnt vmcnt(0)" ::: "memory");
  __builtin_amdgcn_sched_barrier(0);
  __builtin_amdgcn_s_barrier();

#pragma unroll 2
  for (int t = 0; t < NTILE; ++t) {
    const int b = t & 1;
    const bool st = (t + 1 < NTILE);
    const int kn = (t + 1) << 6;
#pragma unroll
    for (int q = 0; q < 4; ++q) {
      if (q == 0) {
#pragma unroll
        for (int nj = 0; nj < BNW; ++nj) {
          RB[nj][0] = *(const bf16x8*)(pB(b, nj) + cb0);
          RB[nj][1] = *(const bf16x8*)(pB(b, nj) + cb1);
        }
      }
      bf16x8 ra[2][2];
#pragma unroll
      for (int m = 0; m < 2; ++m) {
        ra[m][0] = *(const bf16x8*)(pA(b, 2 * q + m) + cb0);
        ra[m][1] = *(const bf16x8*)(pA(b, 2 * q + m) + cb1);
      }
      if (st) {
        if (q == 0) { STAGE_A(b ^ 1, 0, kn); STAGE_A(b ^ 1, 1, kn); }
        else if (q == 1) { STAGE_A(b ^ 1, 2, kn); STAGE_A(b ^ 1, 3, kn); }
        else if (q == 2) { STAGE_B(b ^ 1, 0, kn); STAGE_B(b ^ 1, 1, kn); }
        else if (BNW == 4) { STAGE_B(b ^ 1, 2, kn); STAGE_B(b ^ 1, 3, kn); }
      }
      __builtin_amdgcn_s_barrier();
      asm volatile("s_waitcnt lgkmcnt(0)" ::: "memory");
      __builtin_amdgcn_sched_barrier(0);
      __builtin_amdgcn_s_setprio(1);
#pragma unroll
      for (int nj = 0; nj < BNW; ++nj) {
        acc[2 * q][nj]     = __builtin_amdgcn_mfma_f32_16x16x32_bf16(ra[0][0], RB[nj][0], acc[2 * q][nj], 0, 0, 0);
        acc[2 * q][nj]     = __builtin_amdgcn_mfma_f32_16x16x32_bf16(ra[0][1], RB[nj][1], acc[2 * q][nj], 0, 0, 0);
        acc[2 * q + 1][nj] = __builtin_amdgcn_mfma_f32_16x16x32_bf16(ra[1][0], RB[nj][0], acc[2 * q + 1][nj], 0, 0, 0);
        acc[2 * q + 1][nj] = __builtin_amdgcn_mfma_f32_16x16x32_bf16(ra[1][1], RB[nj][1], acc[2 * q + 1][nj], 0, 0, 0);
      }
      __builtin_amdgcn_s_setprio(0);
      if (q == 3 && st) {
        asm volatile("s_waitcnt vmcnt(0)" ::: "memory");
        __builtin_amdgcn_sched_barrier(0);
      }
      __builtin_amdgcn_s_barrier();
    }
  }

  float* smf = (float*)sc_;
#pragma unroll
  for (int p = 0; p < 2; ++p) {
    if (p) __syncthreads();
    if (wr == p) {
#pragma unroll
      for (int mi = 0; mi < 8; ++mi)
#pragma unroll
        for (int nj = 0; nj < BNW; ++nj) {
          const int colb = wc * (BNW << 4) + (nj << 4) + l15;
          const float bb = bias[bcol + colb];
          const int row0 = (mi << 4) + ((lane >> 4) << 2);
#pragma unroll
          for (int rr = 0; rr < 4; ++rr)
            smf[(row0 + rr) * BN + colb] = acc[mi][nj][rr] + bb;
        }
    }
    __syncthreads();
    constexpr int QPR = BN / 4;
#pragma unroll
    for (int it = 0; it < (128 * QPR) / 512; ++it) {
      const int f = (it << 9) + tid;
      const int row = f / QPR, c4 = f % QPR;
      float4 v = *(const float4*)(smf + row * BN + (c4 << 2));
      *(float4*)(dF + (size_t)(brow + (p << 7) + row) * N + bcol + (c4 << 2)) = v;
    }
  }
}

extern "C" void kernel_launch(void* const* d_in, const int* in_sizes, int n_in,
                              void* d_out, int out_size, void* d_ws, size_t ws_size,
                              hipStream_t stream) {
  const float* q  = (const float*)d_in[0];
  const float* Wq = (const float*)d_in[3];
  const float* bq = (const float*)d_in[4];
  const float* Wk = (const float*)d_in[5];
  const float* bk = (const float*)d_in[6];
  const float* Wv = (const float*)d_in[7];
  const float* bv = (const float*)d_in[8];
  const float* Wo = (const float*)d_in[9];
  const float* bo = (const float*)d_in[10];

  const int C = EMBED;
  const int M = in_sizes[0] / C;                 // 32768
  const size_t xsz = (size_t)M * C;
  const size_t wsz = (size_t)C * C;

  u16* Xb = (u16*)d_out;                         // scratch (overwritten by Wo GEMM)
  u16* Ob = (u16*)d_ws;                          // attention output, bf16 [M][768]
  u16* Wp = Ob + xsz;                            // per-head QKV weights [2304][768]
  u16* Wob = Wp + 3 * wsz;
  float* biasp = (float*)(Wob + wsz);            // 2304 f32 permuted bias

  {
    int n4 = (int)(xsz >> 2);
    cvt_f32_bf16<<<(n4 + 255) / 256, 256, 0, stream>>>(q, Xb, n4);
    int w4 = (int)(wsz >> 2);
    cvt_f32_bf16<<<(w4 + 255) / 256, 256, 0, stream>>>(Wo, Wob, w4);
    cvt_wqkv<<<(2304 * 192 + 255) / 256, 256, 0, stream>>>(Wq, Wk, Wv, bq, bk, bv, Wp, biasp);
  }

  // Fused QKV projection + attention: grid 128 rowblocks x 12 heads = 1536 (6 rounds)
  qkva<<<(M / 256) * HEADS, 512, 0, stream>>>(Xb, Wp, biasp, Ob);

  // Output projection, BN=128: grid 768 = 3 rounds
  gemm256<2, true><<<(M / 256) * (C / 128), 512, 0, stream>>>(
      Ob, Wob, bo, nullptr, nullptr, nullptr, (float*)d_out, C);
}

// Round 9
// 236.948 us; speedup vs baseline: 1.1171x; 1.0746x over previous
//
#include <hip/hip_runtime.h>
#include <hip/hip_bf16.h>

#define EMBED 768
#define HEADS 12
#define WIN 64
#define DH 64
#define KDIM 768
#define NTILE 12      // KDIM / 64

typedef unsigned short u16;
typedef unsigned int u32;
typedef __attribute__((ext_vector_type(8))) short bf16x8;
typedef __attribute__((ext_vector_type(4))) float f32x4;

__device__ __forceinline__ u16 f2bf(float f) {
  union { float f; u32 u; } x; x.f = f;
  return (u16)((x.u + 0x7fffu + ((x.u >> 16) & 1u)) >> 16);
}

// ---------------- fp32 -> bf16 convert ----------------
__global__ void cvt_f32_bf16(const float* __restrict__ in, u16* __restrict__ out, int n4) {
  int i = blockIdx.x * blockDim.x + threadIdx.x;
  if (i >= n4) return;
  float4 v = ((const float4*)in)[i];
  ushort4 o;
  o.x = f2bf(v.x); o.y = f2bf(v.y); o.z = f2bf(v.z); o.w = f2bf(v.w);
  ((ushort4*)out)[i] = o;
}

// Per-head-interleaved QKV weights: out row r = h*192 + {Wq|Wk|Wv}[h*64+d]
__global__ void cvt_wqkv(const float* __restrict__ Wq, const float* __restrict__ Wk,
                         const float* __restrict__ Wv, const float* __restrict__ bq,
                         const float* __restrict__ bk, const float* __restrict__ bv,
                         u16* __restrict__ Wp, float* __restrict__ bp) {
  int i = blockIdx.x * 256 + threadIdx.x;        // one float4 each
  if (i >= 2304 * 192) return;
  int r = i / 192, c4 = i % 192;
  int h = r / 192, t = (r % 192) / 64, d = r % 64;
  const float* W = (t == 0) ? Wq : (t == 1) ? Wk : Wv;
  float4 v = *(const float4*)(W + (size_t)(h * 64 + d) * 768 + c4 * 4);
  ushort4 o;
  o.x = f2bf(v.x); o.y = f2bf(v.y); o.z = f2bf(v.z); o.w = f2bf(v.w);
  *(ushort4*)(Wp + (size_t)r * 768 + c4 * 4) = o;
  if (c4 == 0) {
    const float* bb = (t == 0) ? bq : (t == 1) ? bk : bv;
    bp[r] = bb[h * 64 + d];
  }
}

// ---------------- Fused QKV-projection + window attention ----------------
// Block = 128 rows (2 windows) x 192 cols (head's Q|K|V), 256 thr = 4 waves
// (1M x 4N; per-wave 128 x 48). LDS 80KB -> 2 blocks/CU (independent overlap).
// Main loop: 4 phases/K-tile. Epilogue: scatter acc -> LDS {Q,K row-major
// stride-72; V transposed}, 2-wave-per-window attention, coalesced O out.
__global__ __launch_bounds__(256, 2)
void qkva(const u16* __restrict__ A, const u16* __restrict__ Bw,
          const float* __restrict__ biasp, u16* __restrict__ O) {
  __shared__ char sc_[81920];                    // A 2x16K @0; B 2x24K @32768; attn 54K
  const int tid = threadIdx.x;
  const int lane = tid & 63;
  const int wid = tid >> 6;                      // 0..3
  const int wc = wid;                            // N-split only
  const int l15 = lane & 15;

  const int cpx = gridDim.x >> 3;
  int bid = blockIdx.x;
  bid = (bid & 7) * cpx + (bid >> 3);            // grid 3072 % 8 == 0
  const int head = bid % HEADS;
  const int brow = (bid / HEADS) << 7;
  const int bcolw = head * 192;

  const int srow = tid >> 3;                     // 0..31
  const int scol = ((tid & 7) ^ (srow & 7)) << 3;   // T2 pre-swizzled source
  const u16* Asrc = A + (size_t)(brow + srow) * KDIM + scol;
  const u16* Bsrc = Bw + (size_t)(bcolw + srow) * KDIM + scol;
  const int lds_woff = wid << 10;                // wave base within 4KB unit

  // one unit = 32 rows = 4KB (1 load/thread)
  auto STAGE_A = [&](int b, int u, int kt) {
    __builtin_amdgcn_global_load_lds(
        (const __attribute__((address_space(1))) void*)(Asrc + (size_t)(u << 5) * KDIM + kt),
        (__attribute__((address_space(3))) void*)(sc_ + b * 16384 + (u << 12) + lds_woff), 16, 0, 0);
  };
  auto STAGE_B = [&](int b, int u, int kt) {
    __builtin_amdgcn_global_load_lds(
        (const __attribute__((address_space(1))) void*)(Bsrc + (size_t)(u << 5) * KDIM + kt),
        (__attribute__((address_space(3))) void*)(sc_ + 32768 + b * 24576 + (u << 12) + lds_woff), 16, 0, 0);
  };

  const int swz = (l15 & 7) << 4;
  const int cb0 = ((lane >> 4) << 4) ^ swz;
  const int cb1 = (((lane >> 4) + 4) << 4) ^ swz;
  auto pA = [&](int b, int mi) -> const char* {
    return sc_ + b * 16384 + ((mi << 4) + l15) * 128;
  };
  auto pB = [&](int b, int nj) -> const char* {
    return sc_ + 32768 + b * 24576 + (wc * 48 + (nj << 4) + l15) * 128;
  };

  f32x4 acc[8][3];
#pragma unroll
  for (int m = 0; m < 8; ++m)
#pragma unroll
    for (int n = 0; n < 3; ++n) acc[m][n] = (f32x4){0.f, 0.f, 0.f, 0.f};
  bf16x8 RB[3][2];

  // prologue: stage tile 0 fully
#pragma unroll
  for (int u = 0; u < 4; ++u) STAGE_A(0, u, 0);
#pragma unroll
  for (int u = 0; u < 6; ++u) STAGE_B(0, u, 0);
  asm volatile("s_waitcnt vmcnt(0)" ::: "memory");
  __builtin_amdgcn_sched_barrier(0);
  __builtin_amdgcn_s_barrier();

#pragma unroll 2
  for (int t = 0; t < NTILE; ++t) {
    const int b = t & 1;
    const bool st = (t + 1 < NTILE);
    const int kn = (t + 1) << 6;
#pragma unroll
    for (int q = 0; q < 4; ++q) {
      if (q == 0) {
#pragma unroll
        for (int nj = 0; nj < 3; ++nj) {
          RB[nj][0] = *(const bf16x8*)(pB(b, nj) + cb0);
          RB[nj][1] = *(const bf16x8*)(pB(b, nj) + cb1);
        }
      }
      bf16x8 ra[2][2];
#pragma unroll
      for (int m = 0; m < 2; ++m) {
        ra[m][0] = *(const bf16x8*)(pA(b, 2 * q + m) + cb0);
        ra[m][1] = *(const bf16x8*)(pA(b, 2 * q + m) + cb1);
      }
      if (st) {                                  // 10 units: 3/3/4, none at q3
        if (q == 0) { STAGE_A(b ^ 1, 0, kn); STAGE_A(b ^ 1, 1, kn); STAGE_A(b ^ 1, 2, kn); }
        else if (q == 1) { STAGE_A(b ^ 1, 3, kn); STAGE_B(b ^ 1, 0, kn); STAGE_B(b ^ 1, 1, kn); }
        else if (q == 2) { STAGE_B(b ^ 1, 2, kn); STAGE_B(b ^ 1, 3, kn); STAGE_B(b ^ 1, 4, kn); STAGE_B(b ^ 1, 5, kn); }
      }
      __builtin_amdgcn_s_barrier();
      asm volatile("s_waitcnt lgkmcnt(0)" ::: "memory");
      __builtin_amdgcn_sched_barrier(0);
      __builtin_amdgcn_s_setprio(1);
#pragma unroll
      for (int nj = 0; nj < 3; ++nj) {
        acc[2 * q][nj]     = __builtin_amdgcn_mfma_f32_16x16x32_bf16(ra[0][0], RB[nj][0], acc[2 * q][nj], 0, 0, 0);
        acc[2 * q][nj]     = __builtin_amdgcn_mfma_f32_16x16x32_bf16(ra[0][1], RB[nj][1], acc[2 * q][nj], 0, 0, 0);
        acc[2 * q + 1][nj] = __builtin_amdgcn_mfma_f32_16x16x32_bf16(ra[1][0], RB[nj][0], acc[2 * q + 1][nj], 0, 0, 0);
        acc[2 * q + 1][nj] = __builtin_amdgcn_mfma_f32_16x16x32_bf16(ra[1][1], RB[nj][1], acc[2 * q + 1][nj], 0, 0, 0);
      }
      __builtin_amdgcn_s_setprio(0);
      if (q == 3 && st) {                        // all t+1 stages >=1 phase old
        asm volatile("s_waitcnt vmcnt(0)" ::: "memory");
        __builtin_amdgcn_sched_barrier(0);
      }
      __builtin_amdgcn_s_barrier();
    }
  }

  // ---- epilogue: scatter Q,K (row-major) and V (transposed) into attn LDS ----
  u16* qp  = (u16*)sc_;                          // [2][64][72]  Q, later P
  u16* kk_ = (u16*)(sc_ + 18432);                // [2][64][72]  K, later O
  u16* vv  = (u16*)(sc_ + 36864);                // [2][64][72]  V^T (d-major)
#pragma unroll
  for (int mi = 0; mi < 8; ++mi) {
    const int row0 = (mi << 4) + ((lane >> 4) << 2);
#pragma unroll
    for (int nj = 0; nj < 3; ++nj) {
      const int col = wc * 48 + (nj << 4) + l15;
      const float bb = biasp[bcolw + col];
#pragma unroll
      for (int rr = 0; rr < 4; ++rr) {
        const int rw = row0 + rr;
        const int win = rw >> 6, rloc = rw & 63;
        const u16 val = f2bf(acc[mi][nj][rr] + bb);
        if (col < 64)       qp [win * 4608 + rloc * 72 + col] = val;
        else if (col < 128) kk_[win * 4608 + rloc * 72 + (col - 64)] = val;
        else                vv [win * 4608 + (col - 128) * 72 + rloc] = val;
      }
    }
  }
  __syncthreads();

  // ---- attention: 2 waves per window; this wave owns rows [half*32, +32) ----
  const int w = wid >> 1, half = wid & 1;
  u16* qw = qp + w * 4608;
  u16* kw = kk_ + w * 4608;
  u16* vw = vv + w * 4608;
  const int g8 = (lane >> 4) << 3;
  const int g4 = (lane >> 4) << 2;

  f32x4 sacc[2][4];
#pragma unroll
  for (int m = 0; m < 2; ++m)
#pragma unroll
    for (int t = 0; t < 4; ++t) sacc[m][t] = (f32x4){0.f, 0.f, 0.f, 0.f};
  bf16x8 aq[2][2];
#pragma unroll
  for (int m = 0; m < 2; ++m) {
    const int r = half * 32 + m * 16 + l15;
    aq[m][0] = *(const bf16x8*)(qw + r * 72 + g8);
    aq[m][1] = *(const bf16x8*)(qw + r * 72 + 32 + g8);
  }
#pragma unroll
  for (int t = 0; t < 4; ++t) {
    const int kr = t * 16 + l15;
    bf16x8 bk0 = *(const bf16x8*)(kw + kr * 72 + g8);
    bf16x8 bk1 = *(const bf16x8*)(kw + kr * 72 + 32 + g8);
#pragma unroll
    for (int m = 0; m < 2; ++m) {
      sacc[m][t] = __builtin_amdgcn_mfma_f32_16x16x32_bf16(aq[m][0], bk0, sacc[m][t], 0, 0, 0);
      sacc[m][t] = __builtin_amdgcn_mfma_f32_16x16x32_bf16(aq[m][1], bk1, sacc[m][t], 0, 0, 0);
    }
  }
#pragma unroll
  for (int m = 0; m < 2; ++m)
#pragma unroll
    for (int t = 0; t < 4; ++t)
#pragma unroll
      for (int r = 0; r < 4; ++r) sacc[m][t][r] *= 0.125f;

#pragma unroll
  for (int m = 0; m < 2; ++m)
#pragma unroll
    for (int r = 0; r < 4; ++r) {
      float m0 = fmaxf(fmaxf(sacc[m][0][r], sacc[m][1][r]), fmaxf(sacc[m][2][r], sacc[m][3][r]));
#pragma unroll
      for (int msk = 1; msk < 16; msk <<= 1) m0 = fmaxf(m0, __shfl_xor(m0, msk));
      float s0 = 0.f;
#pragma unroll
      for (int t = 0; t < 4; ++t) {
        float e = __expf(sacc[m][t][r] - m0);
        sacc[m][t][r] = e;
        s0 += e;
      }
#pragma unroll
      for (int msk = 1; msk < 16; msk <<= 1) s0 += __shfl_xor(s0, msk);
      const float inv = 1.f / s0;
#pragma unroll
      for (int t = 0; t < 4; ++t) sacc[m][t][r] *= inv;
    }

  // P -> qw (Q dead; rows disjoint between the wave pair)
#pragma unroll
  for (int m = 0; m < 2; ++m)
#pragma unroll
    for (int t = 0; t < 4; ++t)
#pragma unroll
      for (int r = 0; r < 4; ++r)
        qw[(half * 32 + m * 16 + g4 + r) * 72 + t * 16 + l15] = f2bf(sacc[m][t][r]);

  // PV
  f32x4 oacc[2][4];
#pragma unroll
  for (int m = 0; m < 2; ++m)
#pragma unroll
    for (int t = 0; t < 4; ++t) oacc[m][t] = (f32x4){0.f, 0.f, 0.f, 0.f};
  bf16x8 ap[2][2];
#pragma unroll
  for (int m = 0; m < 2; ++m) {
    const int r = half * 32 + m * 16 + l15;
    ap[m][0] = *(const bf16x8*)(qw + r * 72 + g8);
    ap[m][1] = *(const bf16x8*)(qw + r * 72 + 32 + g8);
  }
#pragma unroll
  for (int t = 0; t < 4; ++t) {
    const int dr = t * 16 + l15;
    bf16x8 bv0 = *(const bf16x8*)(vw + dr * 72 + g8);
    bf16x8 bv1 = *(const bf16x8*)(vw + dr * 72 + 32 + g8);
#pragma unroll
    for (int m = 0; m < 2; ++m) {
      oacc[m][t] = __builtin_amdgcn_mfma_f32_16x16x32_bf16(ap[m][0], bv0, oacc[m][t], 0, 0, 0);
      oacc[m][t] = __builtin_amdgcn_mfma_f32_16x16x32_bf16(ap[m][1], bv1, oacc[m][t], 0, 0, 0);
    }
  }
  __syncthreads();                               // K area dead for all waves
#pragma unroll
  for (int m = 0; m < 2; ++m)
#pragma unroll
    for (int t = 0; t < 4; ++t)
#pragma unroll
      for (int r = 0; r < 4; ++r)
        kw[(half * 32 + m * 16 + g4 + r) * 72 + t * 16 + l15] = f2bf(oacc[m][t][r]);
  __syncthreads();

  // coalesced O store: 128 rows x 128B
#pragma unroll
  for (int it = 0; it < 4; ++it) {
    const int f = (it << 8) + tid;
    const int row = f >> 3, c8 = f & 7;
    uint4 v = *(const uint4*)(kk_ + (row >> 6) * 4608 + (row & 63) * 72 + (c8 << 3));
    *(uint4*)(O + (size_t)(brow + row) * 768 + head * 64 + (c8 << 3)) = v;
  }
}

// ---------------- 128x128 NT GEMM (Wo projection), f32 out, 2 blocks/CU ----------------
__global__ __launch_bounds__(256, 2)
void gemm128(const u16* __restrict__ A, const u16* __restrict__ Bw,
             const float* __restrict__ bias, float* __restrict__ dF, int N) {
  __shared__ char sc_[65536];                    // A 2x16K @0; B 2x16K @32768
  const int tid = threadIdx.x;
  const int lane = tid & 63;
  const int wid = tid >> 6;
  const int wr = wid >> 1, wc = wid & 1;
  const int l15 = lane & 15;

  const int nbx = N >> 7;
  const int cpx = gridDim.x >> 3;
  int bid = blockIdx.x;
  bid = (bid & 7) * cpx + (bid >> 3);            // grid 1536 % 8 == 0
  const int brow = (bid / nbx) << 7;
  const int bcol = (bid % nbx) << 7;

  const int srow = tid >> 3;
  const int scol = ((tid & 7) ^ (srow & 7)) << 3;
  const u16* Asrc = A + (size_t)(brow + srow) * KDIM + scol;
  const u16* Bsrc = Bw + (size_t)(bcol + srow) * KDIM + scol;
  const int lds_woff = wid << 10;

  auto STAGE_A = [&](int b, int u, int kt) {
    __builtin_amdgcn_global_load_lds(
        (const __attribute__((address_space(1))) void*)(Asrc + (size_t)(u << 5) * KDIM + kt),
        (__attribute__((address_space(3))) void*)(sc_ + b * 16384 + (u << 12) + lds_woff), 16, 0, 0);
  };
  auto STAGE_B = [&](int b, int u, int kt) {
    __builtin_amdgcn_global_load_lds(
        (const __attribute__((address_space(1))) void*)(Bsrc + (size_t)(u << 5) * KDIM + kt),
        (__attribute__((address_space(3))) void*)(sc_ + 32768 + b * 16384 + (u << 12) + lds_woff), 16, 0, 0);
  };

  const int swz = (l15 & 7) << 4;
  const int cb0 = ((lane >> 4) << 4) ^ swz;
  const int cb1 = (((lane >> 4) + 4) << 4) ^ swz;
  auto pA = [&](int b, int mi) -> const char* {
    return sc_ + b * 16384 + ((wr << 6) + (mi << 4) + l15) * 128;
  };
  auto pB = [&](int b, int nj) -> const char* {
    return sc_ + 32768 + b * 16384 + ((wc << 6) + (nj << 4) + l15) * 128;
  };

  f32x4 acc[4][4];
#pragma unroll
  for (int m = 0; m < 4; ++m)
#pragma unroll
    for (int n = 0; n < 4; ++n) acc[m][n] = (f32x4){0.f, 0.f, 0.f, 0.f};
  bf16x8 RB[4][2];

#pragma unroll
  for (int u = 0; u < 4; ++u) STAGE_A(0, u, 0);
#pragma unroll
  for (int u = 0; u < 4; ++u) STAGE_B(0, u, 0);
  asm volatile("s_waitcnt vmcnt(0)" ::: "memory");
  __builtin_amdgcn_sched_barrier(0);
  __builtin_amdgcn_s_barrier();

#pragma unroll 2
  for (int t = 0; t < NTILE; ++t) {
    const int b = t & 1;
    const bool st = (t + 1 < NTILE);
    const int kn = (t + 1) << 6;
#pragma unroll
    for (int q = 0; q < 4; ++q) {
      if (q == 0) {
#pragma unroll
        for (int nj = 0; nj < 4; ++nj) {
          RB[nj][0] = *(const bf16x8*)(pB(b, nj) + cb0);
          RB[nj][1] = *(const bf16x8*)(pB(b, nj) + cb1);
        }
      }
      bf16x8 ra[2];
      ra[0] = *(const bf16x8*)(pA(b, q) + cb0);
      ra[1] = *(const bf16x8*)(pA(b, q) + cb1);
      if (st) {                                  // 8 units: 2/2/4, none at q3
        if (q == 0) { STAGE_A(b ^ 1, 0, kn); STAGE_A(b ^ 1, 1, kn); }
        else if (q == 1) { STAGE_A(b ^ 1, 2, kn); STAGE_A(b ^ 1, 3, kn); }
        else if (q == 2) { STAGE_B(b ^ 1, 0, kn); STAGE_B(b ^ 1, 1, kn); STAGE_B(b ^ 1, 2, kn); STAGE_B(b ^ 1, 3, kn); }
      }
      __builtin_amdgcn_s_barrier();
      asm volatile("s_waitcnt lgkmcnt(0)" ::: "memory");
      __builtin_amdgcn_sched_barrier(0);
      __builtin_amdgcn_s_setprio(1);
#pragma unroll
      for (int nj = 0; nj < 4; ++nj) {
        acc[q][nj] = __builtin_amdgcn_mfma_f32_16x16x32_bf16(ra[0], RB[nj][0], acc[q][nj], 0, 0, 0);
        acc[q][nj] = __builtin_amdgcn_mfma_f32_16x16x32_bf16(ra[1], RB[nj][1], acc[q][nj], 0, 0, 0);
      }
      __builtin_amdgcn_s_setprio(0);
      if (q == 3 && st) {
        asm volatile("s_waitcnt vmcnt(0)" ::: "memory");
        __builtin_amdgcn_sched_barrier(0);
      }
      __builtin_amdgcn_s_barrier();
    }
  }

  // f32 epilogue: full 128x128 f32 tile via LDS (64KB), coalesced float4 out
  float* smf = (float*)sc_;
  __syncthreads();
#pragma unroll
  for (int mi = 0; mi < 4; ++mi)
#pragma unroll
    for (int nj = 0; nj < 4; ++nj) {
      const int col = (wc << 6) + (nj << 4) + l15;
      const float bb = bias[bcol + col];
      const int row0 = (wr << 6) + (mi << 4) + ((lane >> 4) << 2);
#pragma unroll
      for (int rr = 0; rr < 4; ++rr)
        smf[(row0 + rr) * 128 + col] = acc[mi][nj][rr] + bb;
    }
  __syncthreads();
#pragma unroll
  for (int it = 0; it < 16; ++it) {
    const int f = (it << 8) + tid;
    const int row = f >> 5, c4 = f & 31;
    float4 v = *(const float4*)(smf + row * 128 + (c4 << 2));
    *(float4*)(dF + (size_t)(brow + row) * N + bcol + (c4 << 2)) = v;
  }
}

extern "C" void kernel_launch(void* const* d_in, const int* in_sizes, int n_in,
                              void* d_out, int out_size, void* d_ws, size_t ws_size,
                              hipStream_t stream) {
  const float* q  = (const float*)d_in[0];
  const float* Wq = (const float*)d_in[3];
  const float* bq = (const float*)d_in[4];
  const float* Wk = (const float*)d_in[5];
  const float* bk = (const float*)d_in[6];
  const float* Wv = (const float*)d_in[7];
  const float* bv = (const float*)d_in[8];
  const float* Wo = (const float*)d_in[9];
  const float* bo = (const float*)d_in[10];

  const int C = EMBED;
  const int M = in_sizes[0] / C;                 // 32768
  const size_t xsz = (size_t)M * C;
  const size_t wsz = (size_t)C * C;

  u16* Xb = (u16*)d_out;                         // scratch (overwritten by Wo GEMM)
  u16* Ob = (u16*)d_ws;                          // attention output, bf16 [M][768]
  u16* Wp = Ob + xsz;                            // per-head QKV weights [2304][768]
  u16* Wob = Wp + 3 * wsz;
  float* biasp = (float*)(Wob + wsz);            // 2304 f32 permuted bias

  {
    int n4 = (int)(xsz >> 2);
    cvt_f32_bf16<<<(n4 + 255) / 256, 256, 0, stream>>>(q, Xb, n4);
    int w4 = (int)(wsz >> 2);
    cvt_f32_bf16<<<(w4 + 255) / 256, 256, 0, stream>>>(Wo, Wob, w4);
    cvt_wqkv<<<(2304 * 192 + 255) / 256, 256, 0, stream>>>(Wq, Wk, Wv, bq, bk, bv, Wp, biasp);
  }

  // Fused QKV projection + attention: 256 rowblocks x 12 heads = 3072 (6 rounds @ 2/CU)
  qkva<<<(M / 128) * HEADS, 256, 0, stream>>>(Xb, Wp, biasp, Ob);

  // Output projection: 256 x 6 = 1536 blocks (3 rounds @ 2/CU)
  gemm128<<<(M / 128) * (C / 128), 256, 0, stream>>>(Ob, Wob, bo, (float*)d_out, C);
}

// Round 10
// 229.703 us; speedup vs baseline: 1.1524x; 1.0315x over previous
//
#include <hip/hip_runtime.h>
#include <hip/hip_bf16.h>

#define EMBED 768
#define HEADS 12
#define WIN 64
#define DH 64
#define KDIM 768
#define NTILE 12      // KDIM / 64

typedef unsigned short u16;
typedef unsigned int u32;
typedef __attribute__((ext_vector_type(8))) short bf16x8;
typedef __attribute__((ext_vector_type(4))) float f32x4;

__device__ __forceinline__ u16 f2bf(float f) {
  union { float f; u32 u; } x; x.f = f;
  return (u16)((x.u + 0x7fffu + ((x.u >> 16) & 1u)) >> 16);
}

// ---------------- fp32 -> bf16 convert ----------------
__global__ void cvt_f32_bf16(const float* __restrict__ in, u16* __restrict__ out, int n4) {
  int i = blockIdx.x * blockDim.x + threadIdx.x;
  if (i >= n4) return;
  float4 v = ((const float4*)in)[i];
  ushort4 o;
  o.x = f2bf(v.x); o.y = f2bf(v.y); o.z = f2bf(v.z); o.w = f2bf(v.w);
  ((ushort4*)out)[i] = o;
}

// Per-head-interleaved QKV weights: out row r = h*192 + {Wq|Wk|Wv}[h*64+d]
__global__ void cvt_wqkv(const float* __restrict__ Wq, const float* __restrict__ Wk,
                         const float* __restrict__ Wv, const float* __restrict__ bq,
                         const float* __restrict__ bk, const float* __restrict__ bv,
                         u16* __restrict__ Wp, float* __restrict__ bp) {
  int i = blockIdx.x * 256 + threadIdx.x;        // one float4 each
  if (i >= 2304 * 192) return;
  int r = i / 192, c4 = i % 192;
  int h = r / 192, t = (r % 192) / 64, d = r % 64;
  const float* W = (t == 0) ? Wq : (t == 1) ? Wk : Wv;
  float4 v = *(const float4*)(W + (size_t)(h * 64 + d) * 768 + c4 * 4);
  ushort4 o;
  o.x = f2bf(v.x); o.y = f2bf(v.y); o.z = f2bf(v.z); o.w = f2bf(v.w);
  *(ushort4*)(Wp + (size_t)r * 768 + c4 * 4) = o;
  if (c4 == 0) {
    const float* bb = (t == 0) ? bq : (t == 1) ? bk : bv;
    bp[r] = bb[h * 64 + d];
  }
}

// ---------------- Fused QKV-projection + window attention ----------------
// Block = 128 rows (2 windows) x 192 cols (head's Q|K|V), 256 thr = 4 waves.
// Double-buffered staging, ONE __syncthreads per K-tile, compiler-scheduled
// interior (no asm waits / sched_barriers / setprio). 2 blocks/CU.
__global__ __launch_bounds__(256, 2)
void qkva(const u16* __restrict__ A, const u16* __restrict__ Bw,
          const float* __restrict__ biasp, u16* __restrict__ O) {
  __shared__ char sc_[81920];                    // A 2x16K @0; B 2x24K @32768; attn 54K
  const int tid = threadIdx.x;
  const int lane = tid & 63;
  const int wid = tid >> 6;                      // 0..3
  const int wc = wid;                            // N-split only
  const int l15 = lane & 15;

  const int cpx = gridDim.x >> 3;
  int bid = blockIdx.x;
  bid = (bid & 7) * cpx + (bid >> 3);            // grid 3072 % 8 == 0
  const int head = bid % HEADS;
  const int brow = (bid / HEADS) << 7;
  const int bcolw = head * 192;

  const int srow = tid >> 3;                     // 0..31
  const int scol = ((tid & 7) ^ (srow & 7)) << 3;   // T2 pre-swizzled source
  const u16* Asrc = A + (size_t)(brow + srow) * KDIM + scol;
  const u16* Bsrc = Bw + (size_t)(bcolw + srow) * KDIM + scol;
  const int lds_woff = wid << 10;

  auto STAGE_A = [&](int b, int u, int kt) {
    __builtin_amdgcn_global_load_lds(
        (const __attribute__((address_space(1))) void*)(Asrc + (size_t)(u << 5) * KDIM + kt),
        (__attribute__((address_space(3))) void*)(sc_ + b * 16384 + (u << 12) + lds_woff), 16, 0, 0);
  };
  auto STAGE_B = [&](int b, int u, int kt) {
    __builtin_amdgcn_global_load_lds(
        (const __attribute__((address_space(1))) void*)(Bsrc + (size_t)(u << 5) * KDIM + kt),
        (__attribute__((address_space(3))) void*)(sc_ + 32768 + b * 24576 + (u << 12) + lds_woff), 16, 0, 0);
  };

  const int swz = (l15 & 7) << 4;
  const int cb0 = ((lane >> 4) << 4) ^ swz;
  const int cb1 = (((lane >> 4) + 4) << 4) ^ swz;
  auto pA = [&](int b, int mi) -> const char* {
    return sc_ + b * 16384 + ((mi << 4) + l15) * 128;
  };
  auto pB = [&](int b, int nj) -> const char* {
    return sc_ + 32768 + b * 24576 + (wc * 48 + (nj << 4) + l15) * 128;
  };

  f32x4 acc[8][3];
#pragma unroll
  for (int m = 0; m < 8; ++m)
#pragma unroll
    for (int n = 0; n < 3; ++n) acc[m][n] = (f32x4){0.f, 0.f, 0.f, 0.f};

  // prologue: stage tile 0
#pragma unroll
  for (int u = 0; u < 4; ++u) STAGE_A(0, u, 0);
#pragma unroll
  for (int u = 0; u < 6; ++u) STAGE_B(0, u, 0);
  __syncthreads();

  for (int t = 0; t < NTILE; ++t) {
    const int b = t & 1;
    if (t + 1 < NTILE) {                         // issue next-tile stage; lands under MFMA
      const int kn = (t + 1) << 6;
#pragma unroll
      for (int u = 0; u < 4; ++u) STAGE_A(b ^ 1, u, kn);
#pragma unroll
      for (int u = 0; u < 6; ++u) STAGE_B(b ^ 1, u, kn);
    }
    bf16x8 rb[3][2];
#pragma unroll
    for (int nj = 0; nj < 3; ++nj) {
      rb[nj][0] = *(const bf16x8*)(pB(b, nj) + cb0);
      rb[nj][1] = *(const bf16x8*)(pB(b, nj) + cb1);
    }
#pragma unroll
    for (int q = 0; q < 4; ++q) {
      bf16x8 ra[2][2];
#pragma unroll
      for (int m = 0; m < 2; ++m) {
        ra[m][0] = *(const bf16x8*)(pA(b, 2 * q + m) + cb0);
        ra[m][1] = *(const bf16x8*)(pA(b, 2 * q + m) + cb1);
      }
#pragma unroll
      for (int nj = 0; nj < 3; ++nj) {
        acc[2 * q][nj]     = __builtin_amdgcn_mfma_f32_16x16x32_bf16(ra[0][0], rb[nj][0], acc[2 * q][nj], 0, 0, 0);
        acc[2 * q][nj]     = __builtin_amdgcn_mfma_f32_16x16x32_bf16(ra[0][1], rb[nj][1], acc[2 * q][nj], 0, 0, 0);
        acc[2 * q + 1][nj] = __builtin_amdgcn_mfma_f32_16x16x32_bf16(ra[1][0], rb[nj][0], acc[2 * q + 1][nj], 0, 0, 0);
        acc[2 * q + 1][nj] = __builtin_amdgcn_mfma_f32_16x16x32_bf16(ra[1][1], rb[nj][1], acc[2 * q + 1][nj], 0, 0, 0);
      }
    }
    __syncthreads();                             // drains; other block on CU covers
  }

  // ---- epilogue: scatter Q,K (row-major) and V (transposed) into attn LDS ----
  u16* qp  = (u16*)sc_;                          // [2][64][72]  Q, later P
  u16* kk_ = (u16*)(sc_ + 18432);                // [2][64][72]  K, later O
  u16* vv  = (u16*)(sc_ + 36864);                // [2][64][72]  V^T (d-major)
#pragma unroll
  for (int mi = 0; mi < 8; ++mi) {
    const int row0 = (mi << 4) + ((lane >> 4) << 2);
#pragma unroll
    for (int nj = 0; nj < 3; ++nj) {
      const int col = wc * 48 + (nj << 4) + l15;
      const float bb = biasp[bcolw + col];
#pragma unroll
      for (int rr = 0; rr < 4; ++rr) {
        const int rw = row0 + rr;
        const int win = rw >> 6, rloc = rw & 63;
        const u16 val = f2bf(acc[mi][nj][rr] + bb);
        if (col < 64)       qp [win * 4608 + rloc * 72 + col] = val;
        else if (col < 128) kk_[win * 4608 + rloc * 72 + (col - 64)] = val;
        else                vv [win * 4608 + (col - 128) * 72 + rloc] = val;
      }
    }
  }
  __syncthreads();

  // ---- attention: 2 waves per window; this wave owns rows [half*32, +32) ----
  const int w = wid >> 1, half = wid & 1;
  u16* qw = qp + w * 4608;
  u16* kw = kk_ + w * 4608;
  u16* vw = vv + w * 4608;
  const int g8 = (lane >> 4) << 3;
  const int g4 = (lane >> 4) << 2;

  f32x4 sacc[2][4];
#pragma unroll
  for (int m = 0; m < 2; ++m)
#pragma unroll
    for (int t = 0; t < 4; ++t) sacc[m][t] = (f32x4){0.f, 0.f, 0.f, 0.f};
  bf16x8 aq[2][2];
#pragma unroll
  for (int m = 0; m < 2; ++m) {
    const int r = half * 32 + m * 16 + l15;
    aq[m][0] = *(const bf16x8*)(qw + r * 72 + g8);
    aq[m][1] = *(const bf16x8*)(qw + r * 72 + 32 + g8);
  }
#pragma unroll
  for (int t = 0; t < 4; ++t) {
    const int kr = t * 16 + l15;
    bf16x8 bk0 = *(const bf16x8*)(kw + kr * 72 + g8);
    bf16x8 bk1 = *(const bf16x8*)(kw + kr * 72 + 32 + g8);
#pragma unroll
    for (int m = 0; m < 2; ++m) {
      sacc[m][t] = __builtin_amdgcn_mfma_f32_16x16x32_bf16(aq[m][0], bk0, sacc[m][t], 0, 0, 0);
      sacc[m][t] = __builtin_amdgcn_mfma_f32_16x16x32_bf16(aq[m][1], bk1, sacc[m][t], 0, 0, 0);
    }
  }
#pragma unroll
  for (int m = 0; m < 2; ++m)
#pragma unroll
    for (int t = 0; t < 4; ++t)
#pragma unroll
      for (int r = 0; r < 4; ++r) sacc[m][t][r] *= 0.125f;

#pragma unroll
  for (int m = 0; m < 2; ++m)
#pragma unroll
    for (int r = 0; r < 4; ++r) {
      float m0 = fmaxf(fmaxf(sacc[m][0][r], sacc[m][1][r]), fmaxf(sacc[m][2][r], sacc[m][3][r]));
#pragma unroll
      for (int msk = 1; msk < 16; msk <<= 1) m0 = fmaxf(m0, __shfl_xor(m0, msk));
      float s0 = 0.f;
#pragma unroll
      for (int t = 0; t < 4; ++t) {
        float e = __expf(sacc[m][t][r] - m0);
        sacc[m][t][r] = e;
        s0 += e;
      }
#pragma unroll
      for (int msk = 1; msk < 16; msk <<= 1) s0 += __shfl_xor(s0, msk);
      const float inv = 1.f / s0;
#pragma unroll
      for (int t = 0; t < 4; ++t) sacc[m][t][r] *= inv;
    }

  // P -> qw (Q dead; rows disjoint between the wave pair)
#pragma unroll
  for (int m = 0; m < 2; ++m)
#pragma unroll
    for (int t = 0; t < 4; ++t)
#pragma unroll
      for (int r = 0; r < 4; ++r)
        qw[(half * 32 + m * 16 + g4 + r) * 72 + t * 16 + l15] = f2bf(sacc[m][t][r]);

  // PV
  f32x4 oacc[2][4];
#pragma unroll
  for (int m = 0; m < 2; ++m)
#pragma unroll
    for (int t = 0; t < 4; ++t) oacc[m][t] = (f32x4){0.f, 0.f, 0.f, 0.f};
  bf16x8 ap[2][2];
#pragma unroll
  for (int m = 0; m < 2; ++m) {
    const int r = half * 32 + m * 16 + l15;
    ap[m][0] = *(const bf16x8*)(qw + r * 72 + g8);
    ap[m][1] = *(const bf16x8*)(qw + r * 72 + 32 + g8);
  }
#pragma unroll
  for (int t = 0; t < 4; ++t) {
    const int dr = t * 16 + l15;
    bf16x8 bv0 = *(const bf16x8*)(vw + dr * 72 + g8);
    bf16x8 bv1 = *(const bf16x8*)(vw + dr * 72 + 32 + g8);
#pragma unroll
    for (int m = 0; m < 2; ++m) {
      oacc[m][t] = __builtin_amdgcn_mfma_f32_16x16x32_bf16(ap[m][0], bv0, oacc[m][t], 0, 0, 0);
      oacc[m][t] = __builtin_amdgcn_mfma_f32_16x16x32_bf16(ap[m][1], bv1, oacc[m][t], 0, 0, 0);
    }
  }
  __syncthreads();                               // K area dead for all waves
#pragma unroll
  for (int m = 0; m < 2; ++m)
#pragma unroll
    for (int t = 0; t < 4; ++t)
#pragma unroll
      for (int r = 0; r < 4; ++r)
        kw[(half * 32 + m * 16 + g4 + r) * 72 + t * 16 + l15] = f2bf(oacc[m][t][r]);
  __syncthreads();

  // coalesced O store: 128 rows x 128B
#pragma unroll
  for (int it = 0; it < 4; ++it) {
    const int f = (it << 8) + tid;
    const int row = f >> 3, c8 = f & 7;
    uint4 v = *(const uint4*)(kk_ + (row >> 6) * 4608 + (row & 63) * 72 + (c8 << 3));
    *(uint4*)(O + (size_t)(brow + row) * 768 + head * 64 + (c8 << 3)) = v;
  }
}

// ---------------- 128x128 NT GEMM (Wo), m97-style single-buffer, 3 blocks/CU ----------------
__global__ __launch_bounds__(256, 3)
void gemm128(const u16* __restrict__ A, const u16* __restrict__ Bw,
             const float* __restrict__ bias, float* __restrict__ dF, int N) {
  __shared__ char sc_[32768];                    // A 16K @0; B 16K @16384 (single buf)
  const int tid = threadIdx.x;
  const int lane = tid & 63;
  const int wid = tid >> 6;
  const int wr = wid >> 1, wc = wid & 1;
  const int l15 = lane & 15;

  const int nbx = N >> 7;
  const int cpx = gridDim.x >> 3;
  int bid = blockIdx.x;
  bid = (bid & 7) * cpx + (bid >> 3);            // grid 1536 % 8 == 0
  const int brow = (bid / nbx) << 7;
  const int bcol = (bid % nbx) << 7;

  const int srow = tid >> 3;
  const int scol = ((tid & 7) ^ (srow & 7)) << 3;
  const u16* Asrc = A + (size_t)(brow + srow) * KDIM + scol;
  const u16* Bsrc = Bw + (size_t)(bcol + srow) * KDIM + scol;
  const int lds_woff = wid << 10;

  auto STAGE_A = [&](int u, int kt) {
    __builtin_amdgcn_global_load_lds(
        (const __attribute__((address_space(1))) void*)(Asrc + (size_t)(u << 5) * KDIM + kt),
        (__attribute__((address_space(3))) void*)(sc_ + (u << 12) + lds_woff), 16, 0, 0);
  };
  auto STAGE_B = [&](int u, int kt) {
    __builtin_amdgcn_global_load_lds(
        (const __attribute__((address_space(1))) void*)(Bsrc + (size_t)(u << 5) * KDIM + kt),
        (__attribute__((address_space(3))) void*)(sc_ + 16384 + (u << 12) + lds_woff), 16, 0, 0);
  };

  const int swz = (l15 & 7) << 4;
  const int cb0 = ((lane >> 4) << 4) ^ swz;
  const int cb1 = (((lane >> 4) + 4) << 4) ^ swz;
  auto pA = [&](int mi) -> const char* {
    return sc_ + (((wr << 6) + (mi << 4) + l15)) * 128;
  };
  auto pB = [&](int nj) -> const char* {
    return sc_ + 16384 + (((wc << 6) + (nj << 4) + l15)) * 128;
  };

  f32x4 acc[4][4];
#pragma unroll
  for (int m = 0; m < 4; ++m)
#pragma unroll
    for (int n = 0; n < 4; ++n) acc[m][n] = (f32x4){0.f, 0.f, 0.f, 0.f};

  for (int t = 0; t < NTILE; ++t) {
    const int kt = t << 6;
#pragma unroll
    for (int u = 0; u < 4; ++u) STAGE_A(u, kt);
#pragma unroll
    for (int u = 0; u < 4; ++u) STAGE_B(u, kt);
    __syncthreads();                             // stage landed (vmcnt drained here)
    bf16x8 rb[4][2];
#pragma unroll
    for (int nj = 0; nj < 4; ++nj) {
      rb[nj][0] = *(const bf16x8*)(pB(nj) + cb0);
      rb[nj][1] = *(const bf16x8*)(pB(nj) + cb1);
    }
#pragma unroll
    for (int q = 0; q < 4; ++q) {
      bf16x8 ra0 = *(const bf16x8*)(pA(q) + cb0);
      bf16x8 ra1 = *(const bf16x8*)(pA(q) + cb1);
#pragma unroll
      for (int nj = 0; nj < 4; ++nj) {
        acc[q][nj] = __builtin_amdgcn_mfma_f32_16x16x32_bf16(ra0, rb[nj][0], acc[q][nj], 0, 0, 0);
        acc[q][nj] = __builtin_amdgcn_mfma_f32_16x16x32_bf16(ra1, rb[nj][1], acc[q][nj], 0, 0, 0);
      }
    }
    __syncthreads();                             // all reads done before re-stage
  }

  // f32 epilogue: two col-half passes via 32KB LDS (128x64 f32)
  float* smf = (float*)sc_;
#pragma unroll
  for (int p = 0; p < 2; ++p) {
    if (p) __syncthreads();
    if (wc == p) {
#pragma unroll
      for (int mi = 0; mi < 4; ++mi)
#pragma unroll
        for (int nj = 0; nj < 4; ++nj) {
          const int col = (nj << 4) + l15;       // 0..63 within half
          const float bb = bias[bcol + (p << 6) + col];
          const int row0 = (wr << 6) + (mi << 4) + ((lane >> 4) << 2);
#pragma unroll
          for (int rr = 0; rr < 4; ++rr)
            smf[(row0 + rr) << 6 | col] = acc[mi][nj][rr] + bb;
        }
    }
    __syncthreads();
#pragma unroll
    for (int it = 0; it < 8; ++it) {
      const int f = (it << 8) + tid;
      const int row = f >> 4, c4 = f & 15;
      float4 v = *(const float4*)(smf + (row << 6) + (c4 << 2));
      *(float4*)(dF + (size_t)(brow + row) * N + bcol + (p << 6) + (c4 << 2)) = v;
    }
  }
}

extern "C" void kernel_launch(void* const* d_in, const int* in_sizes, int n_in,
                              void* d_out, int out_size, void* d_ws, size_t ws_size,
                              hipStream_t stream) {
  const float* q  = (const float*)d_in[0];
  const float* Wq = (const float*)d_in[3];
  const float* bq = (const float*)d_in[4];
  const float* Wk = (const float*)d_in[5];
  const float* bk = (const float*)d_in[6];
  const float* Wv = (const float*)d_in[7];
  const float* bv = (const float*)d_in[8];
  const float* Wo = (const float*)d_in[9];
  const float* bo = (const float*)d_in[10];

  const int C = EMBED;
  const int M = in_sizes[0] / C;                 // 32768
  const size_t xsz = (size_t)M * C;
  const size_t wsz = (size_t)C * C;

  u16* Xb = (u16*)d_out;                         // scratch (overwritten by Wo GEMM)
  u16* Ob = (u16*)d_ws;                          // attention output, bf16 [M][768]
  u16* Wp = Ob + xsz;                            // per-head QKV weights [2304][768]
  u16* Wob = Wp + 3 * wsz;
  float* biasp = (float*)(Wob + wsz);            // 2304 f32 permuted bias

  {
    int n4 = (int)(xsz >> 2);
    cvt_f32_bf16<<<(n4 + 255) / 256, 256, 0, stream>>>(q, Xb, n4);
    int w4 = (int)(wsz >> 2);
    cvt_f32_bf16<<<(w4 + 255) / 256, 256, 0, stream>>>(Wo, Wob, w4);
    cvt_wqkv<<<(2304 * 192 + 255) / 256, 256, 0, stream>>>(Wq, Wk, Wv, bq, bk, bv, Wp, biasp);
  }

  // Fused QKV projection + attention: 256 rowblocks x 12 heads = 3072 (6 rounds @ 2/CU)
  qkva<<<(M / 128) * HEADS, 256, 0, stream>>>(Xb, Wp, biasp, Ob);

  // Output projection: 1536 blocks (2 rounds @ 3/CU)
  gemm128<<<(M / 128) * (C / 128), 256, 0, stream>>>(Ob, Wob, bo, (float*)d_out, C);
}

// Round 11
// 215.378 us; speedup vs baseline: 1.2290x; 1.0665x over previous
//
#include <hip/hip_runtime.h>
#include <hip/hip_bf16.h>

#define EMBED 768
#define HEADS 12
#define WIN 64
#define DH 64
#define KDIM 768
#define NTILE 12      // KDIM / 64

typedef unsigned short u16;
typedef unsigned int u32;
typedef __attribute__((ext_vector_type(8))) short bf16x8;
typedef __attribute__((ext_vector_type(4))) float f32x4;

__device__ __forceinline__ u16 f2bf(float f) {
  union { float f; u32 u; } x; x.f = f;
  return (u16)((x.u + 0x7fffu + ((x.u >> 16) & 1u)) >> 16);
}

// ---------------- fp32 -> bf16 convert ----------------
__global__ void cvt_f32_bf16(const float* __restrict__ in, u16* __restrict__ out, int n4) {
  int i = blockIdx.x * blockDim.x + threadIdx.x;
  if (i >= n4) return;
  float4 v = ((const float4*)in)[i];
  ushort4 o;
  o.x = f2bf(v.x); o.y = f2bf(v.y); o.z = f2bf(v.z); o.w = f2bf(v.w);
  ((ushort4*)out)[i] = o;
}

// Per-head-interleaved QKV weights: out row r = h*192 + {Wq|Wk|Wv}[h*64+d]
__global__ void cvt_wqkv(const float* __restrict__ Wq, const float* __restrict__ Wk,
                         const float* __restrict__ Wv, const float* __restrict__ bq,
                         const float* __restrict__ bk, const float* __restrict__ bv,
                         u16* __restrict__ Wp, float* __restrict__ bp) {
  int i = blockIdx.x * 256 + threadIdx.x;        // one float4 each
  if (i >= 2304 * 192) return;
  int r = i / 192, c4 = i % 192;
  int h = r / 192, t = (r % 192) / 64, d = r % 64;
  const float* W = (t == 0) ? Wq : (t == 1) ? Wk : Wv;
  float4 v = *(const float4*)(W + (size_t)(h * 64 + d) * 768 + c4 * 4);
  ushort4 o;
  o.x = f2bf(v.x); o.y = f2bf(v.y); o.z = f2bf(v.z); o.w = f2bf(v.w);
  *(ushort4*)(Wp + (size_t)r * 768 + c4 * 4) = o;
  if (c4 == 0) {
    const float* bb = (t == 0) ? bq : (t == 1) ? bk : bv;
    bp[r] = bb[h * 64 + d];
  }
}

// ---------------- Fused QKV-projection + window attention ----------------
// Block = 128 rows (2 windows) x 192 cols (head's Q|K|V), 512 thr = 8 waves
// (2M x 4N; per-wave 64 x 48). LDS 80KB -> 2 blocks/CU = 16 waves/CU = 4/SIMD.
// Compiler-scheduled interior, one __syncthreads per K-tile. Attention epilogue:
// 4 waves/window, each owns 16 rows.
__global__ __launch_bounds__(512, 4)
void qkva(const u16* __restrict__ A, const u16* __restrict__ Bw,
          const float* __restrict__ biasp, u16* __restrict__ O) {
  __shared__ char sc_[81920];                    // A 2x16K @0; B 2x24K @32768; attn 54K
  const int tid = threadIdx.x;
  const int lane = tid & 63;
  const int wid = tid >> 6;                      // 0..7
  const int wr = wid >> 2, wc = wid & 3;
  const int l15 = lane & 15;

  const int cpx = gridDim.x >> 3;
  int bid = blockIdx.x;
  bid = (bid & 7) * cpx + (bid >> 3);            // grid 3072 % 8 == 0
  const int head = bid % HEADS;
  const int brow = (bid / HEADS) << 7;
  const int bcolw = head * 192;

  const int srow = tid >> 3;                     // 0..63
  const int scol = ((tid & 7) ^ (srow & 7)) << 3;   // T2 pre-swizzled source
  const u16* Asrc = A + (size_t)(brow + srow) * KDIM + scol;
  const u16* Bsrc = Bw + (size_t)(bcolw + srow) * KDIM + scol;

  // one stage call = 64 rows = 8KB (512 thr x 16B)
  auto STAGE_A = [&](int b, int u, int kt) {
    __builtin_amdgcn_global_load_lds(
        (const __attribute__((address_space(1))) void*)(Asrc + (size_t)(u << 6) * KDIM + kt),
        (__attribute__((address_space(3))) void*)(sc_ + b * 16384 + (u << 13) + tid * 16), 16, 0, 0);
  };
  auto STAGE_B = [&](int b, int u, int kt) {
    __builtin_amdgcn_global_load_lds(
        (const __attribute__((address_space(1))) void*)(Bsrc + (size_t)(u << 6) * KDIM + kt),
        (__attribute__((address_space(3))) void*)(sc_ + 32768 + b * 24576 + (u << 13) + tid * 16), 16, 0, 0);
  };

  const int swz = (l15 & 7) << 4;
  const int cb0 = ((lane >> 4) << 4) ^ swz;
  const int cb1 = (((lane >> 4) + 4) << 4) ^ swz;
  auto pA = [&](int b, int mi) -> const char* {
    return sc_ + b * 16384 + ((wr << 6) + (mi << 4) + l15) * 128;
  };
  auto pB = [&](int b, int nj) -> const char* {
    return sc_ + 32768 + b * 24576 + (wc * 48 + (nj << 4) + l15) * 128;
  };

  f32x4 acc[4][3];
#pragma unroll
  for (int m = 0; m < 4; ++m)
#pragma unroll
    for (int n = 0; n < 3; ++n) acc[m][n] = (f32x4){0.f, 0.f, 0.f, 0.f};

  // prologue: stage tile 0
#pragma unroll
  for (int u = 0; u < 2; ++u) STAGE_A(0, u, 0);
#pragma unroll
  for (int u = 0; u < 3; ++u) STAGE_B(0, u, 0);
  __syncthreads();

  for (int t = 0; t < NTILE; ++t) {
    const int b = t & 1;
    if (t + 1 < NTILE) {                         // next-tile stage lands under MFMA
      const int kn = (t + 1) << 6;
#pragma unroll
      for (int u = 0; u < 2; ++u) STAGE_A(b ^ 1, u, kn);
#pragma unroll
      for (int u = 0; u < 3; ++u) STAGE_B(b ^ 1, u, kn);
    }
    bf16x8 rb[3][2];
#pragma unroll
    for (int nj = 0; nj < 3; ++nj) {
      rb[nj][0] = *(const bf16x8*)(pB(b, nj) + cb0);
      rb[nj][1] = *(const bf16x8*)(pB(b, nj) + cb1);
    }
#pragma unroll
    for (int mi = 0; mi < 4; ++mi) {
      bf16x8 ra0 = *(const bf16x8*)(pA(b, mi) + cb0);
      bf16x8 ra1 = *(const bf16x8*)(pA(b, mi) + cb1);
#pragma unroll
      for (int nj = 0; nj < 3; ++nj) {
        acc[mi][nj] = __builtin_amdgcn_mfma_f32_16x16x32_bf16(ra0, rb[nj][0], acc[mi][nj], 0, 0, 0);
        acc[mi][nj] = __builtin_amdgcn_mfma_f32_16x16x32_bf16(ra1, rb[nj][1], acc[mi][nj], 0, 0, 0);
      }
    }
    __syncthreads();                             // other block + 3 sibling waves cover drain
  }

  // ---- epilogue: scatter Q,K (row-major) and V (transposed) into attn LDS ----
  u16* qp  = (u16*)sc_;                          // [2][64][72]  Q, later P
  u16* kk_ = (u16*)(sc_ + 18432);                // [2][64][72]  K, later O
  u16* vv  = (u16*)(sc_ + 36864);                // [2][64][72]  V^T (d-major)
#pragma unroll
  for (int mi = 0; mi < 4; ++mi) {
    const int row0 = (wr << 6) + (mi << 4) + ((lane >> 4) << 2);
#pragma unroll
    for (int nj = 0; nj < 3; ++nj) {
      const int col = wc * 48 + (nj << 4) + l15;
      const float bb = biasp[bcolw + col];
#pragma unroll
      for (int rr = 0; rr < 4; ++rr) {
        const int rw = row0 + rr;
        const int win = rw >> 6, rloc = rw & 63;
        const u16 val = f2bf(acc[mi][nj][rr] + bb);
        if (col < 64)       qp [win * 4608 + rloc * 72 + col] = val;
        else if (col < 128) kk_[win * 4608 + rloc * 72 + (col - 64)] = val;
        else                vv [win * 4608 + (col - 128) * 72 + rloc] = val;
      }
    }
  }
  __syncthreads();

  // ---- attention: 4 waves per window; this wave owns rows [qt*16, +16) ----
  const int w = wid >> 2, qt = wid & 3;
  u16* qw = qp + w * 4608;
  u16* kw = kk_ + w * 4608;
  u16* vw = vv + w * 4608;
  const int g8 = (lane >> 4) << 3;
  const int g4 = (lane >> 4) << 2;
  const int rown = qt * 16 + l15;

  f32x4 sacc[4];
#pragma unroll
  for (int t = 0; t < 4; ++t) sacc[t] = (f32x4){0.f, 0.f, 0.f, 0.f};
  bf16x8 aq0 = *(const bf16x8*)(qw + rown * 72 + g8);
  bf16x8 aq1 = *(const bf16x8*)(qw + rown * 72 + 32 + g8);
#pragma unroll
  for (int t = 0; t < 4; ++t) {
    const int kr = t * 16 + l15;
    bf16x8 bk0 = *(const bf16x8*)(kw + kr * 72 + g8);
    bf16x8 bk1 = *(const bf16x8*)(kw + kr * 72 + 32 + g8);
    sacc[t] = __builtin_amdgcn_mfma_f32_16x16x32_bf16(aq0, bk0, sacc[t], 0, 0, 0);
    sacc[t] = __builtin_amdgcn_mfma_f32_16x16x32_bf16(aq1, bk1, sacc[t], 0, 0, 0);
  }
#pragma unroll
  for (int t = 0; t < 4; ++t)
#pragma unroll
    for (int r = 0; r < 4; ++r) sacc[t][r] *= 0.125f;

#pragma unroll
  for (int r = 0; r < 4; ++r) {
    float m0 = fmaxf(fmaxf(sacc[0][r], sacc[1][r]), fmaxf(sacc[2][r], sacc[3][r]));
#pragma unroll
    for (int msk = 1; msk < 16; msk <<= 1) m0 = fmaxf(m0, __shfl_xor(m0, msk));
    float s0 = 0.f;
#pragma unroll
    for (int t = 0; t < 4; ++t) {
      float e = __expf(sacc[t][r] - m0);
      sacc[t][r] = e;
      s0 += e;
    }
#pragma unroll
    for (int msk = 1; msk < 16; msk <<= 1) s0 += __shfl_xor(s0, msk);
    const float inv = 1.f / s0;
#pragma unroll
    for (int t = 0; t < 4; ++t) sacc[t][r] *= inv;
  }

  // P -> qw (Q dead; each wave writes only its own 16 rows)
#pragma unroll
  for (int t = 0; t < 4; ++t)
#pragma unroll
    for (int r = 0; r < 4; ++r)
      qw[(qt * 16 + g4 + r) * 72 + t * 16 + l15] = f2bf(sacc[t][r]);

  // PV
  f32x4 oacc[4];
#pragma unroll
  for (int t = 0; t < 4; ++t) oacc[t] = (f32x4){0.f, 0.f, 0.f, 0.f};
  bf16x8 ap0 = *(const bf16x8*)(qw + rown * 72 + g8);
  bf16x8 ap1 = *(const bf16x8*)(qw + rown * 72 + 32 + g8);
#pragma unroll
  for (int t = 0; t < 4; ++t) {
    const int dr = t * 16 + l15;
    bf16x8 bv0 = *(const bf16x8*)(vw + dr * 72 + g8);
    bf16x8 bv1 = *(const bf16x8*)(vw + dr * 72 + 32 + g8);
    oacc[t] = __builtin_amdgcn_mfma_f32_16x16x32_bf16(ap0, bv0, oacc[t], 0, 0, 0);
    oacc[t] = __builtin_amdgcn_mfma_f32_16x16x32_bf16(ap1, bv1, oacc[t], 0, 0, 0);
  }
  __syncthreads();                               // all QK^T reads of kw done
#pragma unroll
  for (int t = 0; t < 4; ++t)
#pragma unroll
    for (int r = 0; r < 4; ++r)
      kw[(qt * 16 + g4 + r) * 72 + t * 16 + l15] = f2bf(oacc[t][r]);
  __syncthreads();

  // coalesced O store: 128 rows x 128B (2 iters x 8KB)
#pragma unroll
  for (int it = 0; it < 2; ++it) {
    const int f = (it << 9) + tid;
    const int row = f >> 3, c8 = f & 7;
    uint4 v = *(const uint4*)(kk_ + (row >> 6) * 4608 + (row & 63) * 72 + (c8 << 3));
    *(uint4*)(O + (size_t)(brow + row) * 768 + head * 64 + (c8 << 3)) = v;
  }
}

// ---------------- 128x128 NT GEMM (Wo), m97-style single-buffer, 3 blocks/CU ----------------
__global__ __launch_bounds__(256, 3)
void gemm128(const u16* __restrict__ A, const u16* __restrict__ Bw,
             const float* __restrict__ bias, float* __restrict__ dF, int N) {
  __shared__ char sc_[32768];                    // A 16K @0; B 16K @16384 (single buf)
  const int tid = threadIdx.x;
  const int lane = tid & 63;
  const int wid = tid >> 6;
  const int wr = wid >> 1, wc = wid & 1;
  const int l15 = lane & 15;

  const int nbx = N >> 7;
  const int cpx = gridDim.x >> 3;
  int bid = blockIdx.x;
  bid = (bid & 7) * cpx + (bid >> 3);            // grid 1536 % 8 == 0
  const int brow = (bid / nbx) << 7;
  const int bcol = (bid % nbx) << 7;

  const int srow = tid >> 3;
  const int scol = ((tid & 7) ^ (srow & 7)) << 3;
  const u16* Asrc = A + (size_t)(brow + srow) * KDIM + scol;
  const u16* Bsrc = Bw + (size_t)(bcol + srow) * KDIM + scol;
  const int lds_woff = wid << 10;

  auto STAGE_A = [&](int u, int kt) {
    __builtin_amdgcn_global_load_lds(
        (const __attribute__((address_space(1))) void*)(Asrc + (size_t)(u << 5) * KDIM + kt),
        (__attribute__((address_space(3))) void*)(sc_ + (u << 12) + lds_woff), 16, 0, 0);
  };
  auto STAGE_B = [&](int u, int kt) {
    __builtin_amdgcn_global_load_lds(
        (const __attribute__((address_space(1))) void*)(Bsrc + (size_t)(u << 5) * KDIM + kt),
        (__attribute__((address_space(3))) void*)(sc_ + 16384 + (u << 12) + lds_woff), 16, 0, 0);
  };

  const int swz = (l15 & 7) << 4;
  const int cb0 = ((lane >> 4) << 4) ^ swz;
  const int cb1 = (((lane >> 4) + 4) << 4) ^ swz;
  auto pA = [&](int mi) -> const char* {
    return sc_ + (((wr << 6) + (mi << 4) + l15)) * 128;
  };
  auto pB = [&](int nj) -> const char* {
    return sc_ + 16384 + (((wc << 6) + (nj << 4) + l15)) * 128;
  };

  f32x4 acc[4][4];
#pragma unroll
  for (int m = 0; m < 4; ++m)
#pragma unroll
    for (int n = 0; n < 4; ++n) acc[m][n] = (f32x4){0.f, 0.f, 0.f, 0.f};

  for (int t = 0; t < NTILE; ++t) {
    const int kt = t << 6;
#pragma unroll
    for (int u = 0; u < 4; ++u) STAGE_A(u, kt);
#pragma unroll
    for (int u = 0; u < 4; ++u) STAGE_B(u, kt);
    __syncthreads();                             // stage landed
    bf16x8 rb[4][2];
#pragma unroll
    for (int nj = 0; nj < 4; ++nj) {
      rb[nj][0] = *(const bf16x8*)(pB(nj) + cb0);
      rb[nj][1] = *(const bf16x8*)(pB(nj) + cb1);
    }
#pragma unroll
    for (int q = 0; q < 4; ++q) {
      bf16x8 ra0 = *(const bf16x8*)(pA(q) + cb0);
      bf16x8 ra1 = *(const bf16x8*)(pA(q) + cb1);
#pragma unroll
      for (int nj = 0; nj < 4; ++nj) {
        acc[q][nj] = __builtin_amdgcn_mfma_f32_16x16x32_bf16(ra0, rb[nj][0], acc[q][nj], 0, 0, 0);
        acc[q][nj] = __builtin_amdgcn_mfma_f32_16x16x32_bf16(ra1, rb[nj][1], acc[q][nj], 0, 0, 0);
      }
    }
    __syncthreads();                             // all reads done before re-stage
  }

  // f32 epilogue: two col-half passes via 32KB LDS (128x64 f32)
  float* smf = (float*)sc_;
#pragma unroll
  for (int p = 0; p < 2; ++p) {
    if (p) __syncthreads();
    if (wc == p) {
#pragma unroll
      for (int mi = 0; mi < 4; ++mi)
#pragma unroll
        for (int nj = 0; nj < 4; ++nj) {
          const int col = (nj << 4) + l15;
          const float bb = bias[bcol + (p << 6) + col];
          const int row0 = (wr << 6) + (mi << 4) + ((lane >> 4) << 2);
#pragma unroll
          for (int rr = 0; rr < 4; ++rr)
            smf[(row0 + rr) << 6 | col] = acc[mi][nj][rr] + bb;
        }
    }
    __syncthreads();
#pragma unroll
    for (int it = 0; it < 8; ++it) {
      const int f = (it << 8) + tid;
      const int row = f >> 4, c4 = f & 15;
      float4 v = *(const float4*)(smf + (row << 6) + (c4 << 2));
      *(float4*)(dF + (size_t)(brow + row) * N + bcol + (p << 6) + (c4 << 2)) = v;
    }
  }
}

extern "C" void kernel_launch(void* const* d_in, const int* in_sizes, int n_in,
                              void* d_out, int out_size, void* d_ws, size_t ws_size,
                              hipStream_t stream) {
  const float* q  = (const float*)d_in[0];
  const float* Wq = (const float*)d_in[3];
  const float* bq = (const float*)d_in[4];
  const float* Wk = (const float*)d_in[5];
  const float* bk = (const float*)d_in[6];
  const float* Wv = (const float*)d_in[7];
  const float* bv = (const float*)d_in[8];
  const float* Wo = (const float*)d_in[9];
  const float* bo = (const float*)d_in[10];

  const int C = EMBED;
  const int M = in_sizes[0] / C;                 // 32768
  const size_t xsz = (size_t)M * C;
  const size_t wsz = (size_t)C * C;

  u16* Xb = (u16*)d_out;                         // scratch (overwritten by Wo GEMM)
  u16* Ob = (u16*)d_ws;                          // attention output, bf16 [M][768]
  u16* Wp = Ob + xsz;                            // per-head QKV weights [2304][768]
  u16* Wob = Wp + 3 * wsz;
  float* biasp = (float*)(Wob + wsz);            // 2304 f32 permuted bias

  {
    int n4 = (int)(xsz >> 2);
    cvt_f32_bf16<<<(n4 + 255) / 256, 256, 0, stream>>>(q, Xb, n4);
    int w4 = (int)(wsz >> 2);
    cvt_f32_bf16<<<(w4 + 255) / 256, 256, 0, stream>>>(Wo, Wob, w4);
    cvt_wqkv<<<(2304 * 192 + 255) / 256, 256, 0, stream>>>(Wq, Wk, Wv, bq, bk, bv, Wp, biasp);
  }

  // Fused QKV projection + attention: 256 rowblocks x 12 heads = 3072 blocks
  qkva<<<(M / 128) * HEADS, 512, 0, stream>>>(Xb, Wp, biasp, Ob);

  // Output projection: 1536 blocks (2 rounds @ 3/CU)
  gemm128<<<(M / 128) * (C / 128), 256, 0, stream>>>(Ob, Wob, bo, (float*)d_out, C);
}